// Round 10
// baseline (296.957 us; speedup 1.0000x reference)
//
#include <hip/hip_runtime.h>
#include <stdint.h>

// FP32 in/out (R4). bf16 only for MFMA operands.
// R6: no cooperative mega-kernel. R7/R9: weight prefetch into POD register
// arrays (union arrays spill -- R8). R9 analysis: k_fused is barrier-domain
// bound at 1 block/CU -> split graphs across 4 blocks (2 heads each),
// last-block combiner with device-scope fences (G16).

#define N_NODES 6144
#define GSIZE 24
#define NGRAPH 256
#define DIN 128
#define DH 64
#define EFF 512
#define EPSN 1e-5f

typedef __attribute__((ext_vector_type(8))) __bf16 bf16x8;
typedef __attribute__((ext_vector_type(4))) float f32x4;
union U16B { uint4 u; bf16x8 v; unsigned short s[8]; };

__device__ inline float bf2f(unsigned short u){ return __uint_as_float(((unsigned)u)<<16); }
__device__ inline unsigned short f2bf(float f){
  unsigned u = __float_as_uint(f);
  u += 0x7fff + ((u>>16)&1);
  return (unsigned short)(u>>16);
}
__device__ inline float gelu_exact(float x){ return 0.5f*x*(1.0f+erff(x*0.70710678118654752f)); }

// ---- workspace float offsets ----
#define XP     0         // 192 x 256: x col stat partials
#define A1C1   49152     // 256 floats: norm1 coeffs (k_pre finisher)
#define HP     49408     // 256 x 128: h col stat partials
#define WT1    82176
#define WT2    86272
#define PWT1   90368
#define FBo    94464     // 257 floats
#define XPCNT  95232     // 1 int  (k_pre finisher counter)   byte 380928
#define CNT    95233     // 256 ints (k_fused combiner cnts)  ends byte 381956
#define WCVT_BYTE  382976    // 3 x 512 x 128 bf16 = 393216 B
#define HPART_BYTE 776192    // 1024 x 24 x 64 fp32 = 6291456 B
#define HCOMB_BYTE 7067648   // 6144 x 64 fp32

// ================= K1: k_pre =================
// blocks 0..191: x col-stat partials; last finisher computes A1/C1.
// blocks 192..194: transpose o_w1/o_w2/p_w1 (+bias staging in 192)
// blocks 195..206: wq/wk/wv -> bf16 (12 segments)
__global__ __launch_bounds__(256)
void k_pre(const float* __restrict__ x,
           const float* __restrict__ o_w1, const float* __restrict__ o_w2,
           const float* __restrict__ p_w1,
           const float* __restrict__ o_b1, const float* __restrict__ o_b2,
           const float* __restrict__ p_b1, const float* __restrict__ p_w2,
           const float* __restrict__ p_b2,
           const float* __restrict__ wq, const float* __restrict__ wk,
           const float* __restrict__ wv,
           const float* __restrict__ nq_w, const float* __restrict__ nq_b,
           const float* __restrict__ nq_ms,
           float* __restrict__ wsf){
  int t = threadIdx.x;
  int bi = blockIdx.x;
  if(bi < 192){
    int c = t & 127, h = t >> 7;
    float s = 0.f, q = 0.f;
    #pragma unroll
    for(int r = 0; r < 16; ++r){
      float v = x[(size_t)(bi*32 + h + 2*r)*DIN + c];
      s += v; q += v*v;
    }
    __shared__ float sm[256], sm2[256];
    __shared__ int lastf;
    sm[t] = s; sm2[t] = q;
    __syncthreads();
    if(t < 128){
      wsf[XP + bi*256 + t]       = sm[t] + sm[t+128];
      wsf[XP + bi*256 + 128 + t] = sm2[t] + sm2[t+128];
    }
    __syncthreads();                 // drain stores
    if(t == 0){
      __threadfence();
      int old = atomicAdd((int*)(wsf + XPCNT), 1);
      lastf = (old == 191);
    }
    __syncthreads();
    if(!lastf) return;
    __threadfence();
    // finisher: reduce 192 partials for idx=t (0..127 sums, 128..255 sumsq)
    float acc = 0.f;
    for(int p = 0; p < 192; ++p) acc += wsf[XP + p*256 + t];
    sm[t] = acc;
    __syncthreads();
    if(t < 128){
      float mean = sm[t] * (1.0f / N_NODES);
      float ex2  = sm[128+t] * (1.0f / N_NODES);
      float cm   = mean * nq_ms[t];
      float var  = ex2 - 2.f*cm*mean + cm*cm;
      float rstd = rsqrtf(var + EPSN);
      float a    = nq_w[t] * rstd;
      wsf[A1C1 + t]       = a;
      wsf[A1C1 + 128 + t] = nq_b[t] - a*cm;
    }
    return;
  }
  if(bi < 195){
    const float* src; float* dst;
    if(bi == 192){ src = o_w1; dst = wsf + WT1; }
    else if(bi == 193){ src = o_w2; dst = wsf + WT2; }
    else { src = p_w1; dst = wsf + PWT1; }
    for(int p = t; p < DH*DH; p += 256){
      int r = p >> 6, c = p & 63;
      dst[c*DH + r] = src[p];
    }
    if(bi == 192){
      float* fb = wsf + FBo;
      if(t < 64){
        fb[t]       = o_b1[t];
        fb[64 + t]  = o_b2[t];
        fb[128 + t] = p_b1[t];
        fb[192 + t] = p_w2[t];
      }
      if(t == 0) fb[256] = p_b2[0];
    }
    return;
  }
  int j = bi - 195;               // 0..11
  int mat = j >> 2, seg = j & 3;
  const float* src = (mat==0) ? wq : (mat==1) ? wk : wv;
  unsigned short* dst = (unsigned short*)((char*)wsf + WCVT_BYTE)
                        + (size_t)mat*EFF*DIN + seg*16384;
  const float* sp = src + seg*16384;
  for(int e = t*8; e < 16384; e += 2048){
    float4 a = *(const float4*)(sp + e);
    float4 b = *(const float4*)(sp + e + 4);
    U16B o;
    o.s[0]=f2bf(a.x); o.s[1]=f2bf(a.y); o.s[2]=f2bf(a.z); o.s[3]=f2bf(a.w);
    o.s[4]=f2bf(b.x); o.s[5]=f2bf(b.y); o.s[6]=f2bf(b.z); o.s[7]=f2bf(b.w);
    *(uint4*)(dst + e) = o.u;
  }
}

// ================= K2: k_fused =================
// 1024 blocks x 256 thr, 4 blocks per graph (2 heads each), 4 blocks/CU.
__global__ __launch_bounds__(256, 4)
void k_fused(const float* __restrict__ x,
             const float* __restrict__ bq, const float* __restrict__ bk,
             const float* __restrict__ bv,
             float* __restrict__ ws, float* __restrict__ hcomb){
  __shared__ __align__(16) float hv[GSIZE][68];
  __shared__ float A1s[128], C1s[128];
  __shared__ __align__(16) float qs[GSIZE][68], ks[GSIZE][68], vs[GSIZE][68];
  __shared__ __align__(16) float S[GSIZE][28];
  __shared__ int lastf;

  int t = threadIdx.x, b = blockIdx.x;
  int g = b >> 2, quarter = b & 3, base = g * GSIZE;
  const unsigned short* wcvt = (const unsigned short*)((const char*)ws + WCVT_BYTE);
  float* hpart = (float*)((char*)ws + HPART_BYTE);

  if(t < 128){ A1s[t] = ws[A1C1 + t]; C1s[t] = ws[A1C1 + 128 + t]; }
  __syncthreads();

  int wv4 = t >> 6, lane = t & 63, m = lane & 15, quad = lane >> 4;
  int mt = wv4 & 1, cth = wv4 >> 1;
  int node = mt*16 + m;
  int xrow = base + ((node < GSIZE) ? node : 0);

  // normalized x fragments (B operand), reused both iters
  bf16x8 xfr[4];
  #pragma unroll
  for(int kk = 0; kk < 4; kk++){
    int k0 = kk*32 + quad*8;
    float4 a = *(const float4*)(x + (size_t)xrow*DIN + k0);
    float4 bfl = *(const float4*)(x + (size_t)xrow*DIN + k0 + 4);
    U16B u;
    u.s[0] = f2bf(a.x*A1s[k0+0] + C1s[k0+0]);
    u.s[1] = f2bf(a.y*A1s[k0+1] + C1s[k0+1]);
    u.s[2] = f2bf(a.z*A1s[k0+2] + C1s[k0+2]);
    u.s[3] = f2bf(a.w*A1s[k0+3] + C1s[k0+3]);
    u.s[4] = f2bf(bfl.x*A1s[k0+4] + C1s[k0+4]);
    u.s[5] = f2bf(bfl.y*A1s[k0+5] + C1s[k0+5]);
    u.s[6] = f2bf(bfl.z*A1s[k0+6] + C1s[k0+6]);
    u.s[7] = f2bf(bfl.w*A1s[k0+7] + C1s[k0+7]);
    xfr[kk] = u.v;
  }

  // POD prefetch buffers (R8 spill lesson)
  uint4 wbuf[6][4];
  float4 bb[6];
  {
    int hh = quarter*2;
    #pragma unroll
    for(int task = 0; task < 6; ++task){
      int tk = cth*6 + task;
      int mat = tk >> 2, ctm = tk & 3;
      const unsigned short* wp = wcvt + (size_t)mat*EFF*DIN
                               + (size_t)(hh*64 + ctm*16 + m)*DIN + quad*8;
      #pragma unroll
      for(int kk = 0; kk < 4; kk++) wbuf[task][kk] = *(const uint4*)(wp + kk*32);
      const float* bias = (mat==0) ? bq : (mat==1) ? bk : bv;
      bb[task] = *(const float4*)(bias + hh*64 + ctm*16 + quad*4);
    }
  }

  f32x4 a0 = {0.f,0.f,0.f,0.f}, a1 = {0.f,0.f,0.f,0.f};

  for(int iter = 0; iter < 2; ++iter){
    __syncthreads();                          // prior PV done; tiles reusable
    #pragma unroll
    for(int task = 0; task < 6; ++task){
      int tk = cth*6 + task;
      int mat = tk >> 2, ctm = tk & 3;
      f32x4 acc = {0.f,0.f,0.f,0.f};
      #pragma unroll
      for(int kk = 0; kk < 4; kk++){
        U16B w8; w8.u = wbuf[task][kk];
        acc = __builtin_amdgcn_mfma_f32_16x16x32_bf16(w8.v, xfr[kk], acc, 0, 0, 0);
      }
      float (*tile)[68] = (mat==0) ? qs : (mat==1) ? ks : vs;
      if(mt == 0 || m < 8){
        int d0 = ctm*16 + quad*4;
        tile[node][d0+0] = acc[0] + bb[task].x;
        tile[node][d0+1] = acc[1] + bb[task].y;
        tile[node][d0+2] = acc[2] + bb[task].z;
        tile[node][d0+3] = acc[3] + bb[task].w;
      }
    }
    __syncthreads();                          // tiles ready
    if(iter == 0){                            // prefetch 2nd head during S+PV
      int hh = quarter*2 + 1;
      #pragma unroll
      for(int task = 0; task < 6; ++task){
        int tk = cth*6 + task;
        int mat = tk >> 2, ctm = tk & 3;
        const unsigned short* wp = wcvt + (size_t)mat*EFF*DIN
                                 + (size_t)(hh*64 + ctm*16 + m)*DIN + quad*8;
        #pragma unroll
        for(int kk = 0; kk < 4; kk++) wbuf[task][kk] = *(const uint4*)(wp + kk*32);
        const float* bias = (mat==0) ? bq : (mat==1) ? bk : bv;
        bb[task] = *(const float4*)(bias + hh*64 + ctm*16 + quad*4);
      }
    }
    // ---- S + softmax fused ----
    if(t < 192){
      int row = t >> 3, sl = t & 7;
      const float4* qi = (const float4*)qs[row];
      const float4* k0p = (const float4*)ks[sl*3];
      const float4* k1p = (const float4*)ks[sl*3+1];
      const float4* k2p = (const float4*)ks[sl*3+2];
      float s0 = 0.f, s1 = 0.f, s2 = 0.f;
      #pragma unroll
      for(int d = 0; d < 16; ++d){
        float4 qv = qi[d];
        float4 ka = k0p[d], kb = k1p[d], kc = k2p[d];
        s0 += qv.x*ka.x + qv.y*ka.y + qv.z*ka.z + qv.w*ka.w;
        s1 += qv.x*kb.x + qv.y*kb.y + qv.z*kb.z + qv.w*kb.w;
        s2 += qv.x*kc.x + qv.y*kc.y + qv.z*kc.z + qv.w*kc.w;
      }
      s0 *= 0.125f; s1 *= 0.125f; s2 *= 0.125f;
      float m0 = fmaxf(fmaxf(s0, s1), s2);
      #pragma unroll
      for(int o = 1; o < 8; o <<= 1) m0 = fmaxf(m0, __shfl_xor(m0, o, 8));
      float e0 = __expf(s0-m0), e1 = __expf(s1-m0), e2 = __expf(s2-m0);
      float su = e0 + e1 + e2;
      #pragma unroll
      for(int o = 1; o < 8; o <<= 1) su += __shfl_xor(su, o, 8);
      float inv = 1.0f / (su + 1e-16f);
      S[row][sl*3]   = e0*inv;
      S[row][sl*3+1] = e1*inv;
      S[row][sl*3+2] = e2*inv;
    }
    __syncthreads();
    // ---- PV accumulate ----
    {
      int i = t >> 4, dq = t & 15;
      #pragma unroll 8
      for(int j = 0; j < GSIZE; ++j){
        float w = S[i][j];
        float4 v = *(const float4*)&vs[j][dq*4];
        a0.x += w*v.x; a0.y += w*v.y; a0.z += w*v.z; a0.w += w*v.w;
      }
      if(t < 128){
        int p = t + 256; int i2 = p >> 4, dq2 = p & 15;
        #pragma unroll 8
        for(int j = 0; j < GSIZE; ++j){
          float w = S[i2][j];
          float4 v = *(const float4*)&vs[j][dq2*4];
          a1.x += w*v.x; a1.y += w*v.y; a1.z += w*v.z; a1.w += w*v.w;
        }
      }
    }
  }
  __syncthreads();
  // ---- write 2-head partial (mean weight 1/8 per head) ----
  {
    int i = t >> 4, dq = t & 15;
    float4 o; o.x = a0.x*0.125f; o.y = a0.y*0.125f; o.z = a0.z*0.125f; o.w = a0.w*0.125f;
    if(quarter == 0){
      const float* xr = x + (size_t)(base+i)*DIN + dq*4;
      float4 r1 = *(const float4*)xr;
      float4 r2 = *(const float4*)(xr + 64);
      o.x += r1.x + r2.x; o.y += r1.y + r2.y; o.z += r1.z + r2.z; o.w += r1.w + r2.w;
    }
    *(float4*)&hv[i][dq*4] = o;
    *(float4*)(hpart + ((size_t)b*GSIZE + i)*DH + dq*4) = o;
    if(t < 128){
      int p = t + 256; int i2 = p >> 4, dq2 = p & 15;
      float4 o2; o2.x = a1.x*0.125f; o2.y = a1.y*0.125f; o2.z = a1.z*0.125f; o2.w = a1.w*0.125f;
      if(quarter == 0){
        const float* xr = x + (size_t)(base+i2)*DIN + dq2*4;
        float4 r1 = *(const float4*)xr;
        float4 r2 = *(const float4*)(xr + 64);
        o2.x += r1.x + r2.x; o2.y += r1.y + r2.y; o2.z += r1.z + r2.z; o2.w += r1.w + r2.w;
      }
      *(float4*)&hv[i2][dq2*4] = o2;
      *(float4*)(hpart + ((size_t)b*GSIZE + i2)*DH + dq2*4) = o2;
    }
  }
  __syncthreads();                 // drain partial stores
  if(t == 0){
    __threadfence();
    int old = atomicAdd((int*)(ws + CNT) + g, 1);
    lastf = (old == 3);
  }
  __syncthreads();
  if(!lastf) return;
  __threadfence();                 // acquire: see peers' partials
  {
    int gb = g << 2;
    int i = t >> 4, dq = t & 15;
    float4 o = *(float4*)&hv[i][dq*4];
    #pragma unroll
    for(int qq = 0; qq < 4; ++qq){
      if(qq == quarter) continue;
      float4 pv = *(const float4*)(hpart + ((size_t)(gb+qq)*GSIZE + i)*DH + dq*4);
      o.x += pv.x; o.y += pv.y; o.z += pv.z; o.w += pv.w;
    }
    *(float4*)&hv[i][dq*4] = o;
    *(float4*)(hcomb + (size_t)(base+i)*DH + dq*4) = o;
    if(t < 128){
      int p = t + 256; int i2 = p >> 4, dq2 = p & 15;
      float4 o2 = *(float4*)&hv[i2][dq2*4];
      #pragma unroll
      for(int qq = 0; qq < 4; ++qq){
        if(qq == quarter) continue;
        float4 pv = *(const float4*)(hpart + ((size_t)(gb+qq)*GSIZE + i2)*DH + dq2*4);
        o2.x += pv.x; o2.y += pv.y; o2.z += pv.z; o2.w += pv.w;
      }
      *(float4*)&hv[i2][dq2*4] = o2;
      *(float4*)(hcomb + (size_t)(base+i2)*DH + dq2*4) = o2;
    }
  }
  __syncthreads();
  if(t < 64){
    float s1 = 0.f, s2 = 0.f;
    #pragma unroll
    for(int i = 0; i < GSIZE; ++i){ float v = hv[i][t]; s1 += v; s2 += v*v; }
    ws[HP + g*128 + t]      = s1;
    ws[HP + g*128 + 64 + t] = s2;
  }
}

// ================= K3: k_final =================
__global__ __launch_bounds__(256)
void k_final(const float* __restrict__ x,
             const float* __restrict__ hbuf, const float* __restrict__ ws,
             const float* __restrict__ no_w, const float* __restrict__ no_b,
             const float* __restrict__ no_ms,
             const float* __restrict__ pn_w, const float* __restrict__ pn_b,
             const float* __restrict__ pn_ms,
             float* __restrict__ out){
  const float* pwt1 = ws + PWT1;
  const float* fb   = ws + FBo;

  __shared__ float wt1s[64][64], wt2s[64][64];   // 32 KB staged weights
  __shared__ float hs[GSIZE][DH];
  __shared__ float hn[GSIZE][DH];
  __shared__ float ts[GSIZE][DH];
  __shared__ float A2[DH], C2[DH];
  __shared__ float a3[DH], c3[DH];
  __shared__ float scores[GSIZE], wsm[GSIZE];
  __shared__ float redA[256], redB[256];

  int t = threadIdx.x;
  int base = blockIdx.x * GSIZE;

  for(int p = t; p < DH*DH; p += 256){
    wt1s[p>>6][p&63] = ws[WT1 + p];
    wt2s[p>>6][p&63] = ws[WT2 + p];
  }
  {
    int c = t & 63, grp = t >> 6;
    float s1 = 0.f, s2 = 0.f;
    for(int p = grp; p < NGRAPH; p += 4){
      s1 += ws[HP + p*128 + c];
      s2 += ws[HP + p*128 + 64 + c];
    }
    redA[t] = s1; redB[t] = s2;
  }
  __syncthreads();
  if(t < DH){
    float s1 = redA[t] + redA[t+64] + redA[t+128] + redA[t+192];
    float s2 = redB[t] + redB[t+64] + redB[t+128] + redB[t+192];
    float mean = s1 * (1.0f / N_NODES);
    float ex2  = s2 * (1.0f / N_NODES);
    float cm   = mean * no_ms[t];
    float var  = ex2 - 2.f*cm*mean + cm*cm;
    float rstd = rsqrtf(var + EPSN);
    float a    = no_w[t] * rstd;
    A2[t] = a; C2[t] = no_b[t] - a*cm;
  }
  __syncthreads();
  for(int p = t; p < GSIZE*DH; p += 256){
    int i = p >> 6, d = p & 63;
    float hvv = hbuf[(size_t)(base+i)*DH + d];
    hs[i][d] = hvv;
    hn[i][d] = A2[d]*hvv + C2[d];
  }
  __syncthreads();
  for(int p = t; p < GSIZE*DH; p += 256){
    int i = p >> 6, c = p & 63;
    float s = fb[c];
    #pragma unroll
    for(int k = 0; k < DH; k++) s += hn[i][k] * wt1s[k][c];
    ts[i][c] = gelu_exact(s);
  }
  __syncthreads();
  for(int p = t; p < GSIZE*DH; p += 256){
    int i = p >> 6, c = p & 63;
    float s = fb[64 + c];
    #pragma unroll
    for(int k = 0; k < DH; k++) s += ts[i][k] * wt2s[k][c];
    hs[i][c] = hs[i][c] + s;
  }
  __syncthreads();
  if(t < DH){
    float s1 = 0.f, s2 = 0.f;
    for(int i = 0; i < GSIZE; i++){ float v = hs[i][t]; s1 += v; s2 += v*v; }
    float mean = s1 * (1.0f / GSIZE);
    float ex2  = s2 * (1.0f / GSIZE);
    float cm   = mean * pn_ms[t];
    float var  = ex2 - 2.f*cm*mean + cm*cm;
    float rstd = rsqrtf(var + EPSN);
    float a    = pn_w[t] * rstd;
    a3[t] = a; c3[t] = pn_b[t] - a*cm;
  }
  __syncthreads();
  for(int p = t; p < GSIZE*DH; p += 256){
    int i = p >> 6, d = p & 63;
    hn[i][d] = a3[d]*hs[i][d] + c3[d];
  }
  __syncthreads();
  for(int p = t; p < GSIZE*DH; p += 256){
    int i = p >> 6, c = p & 63;
    float s = fb[128 + c];
    #pragma unroll
    for(int k = 0; k < DH; k++) s += hn[i][k] * pwt1[k*DH + c];
    ts[i][c] = gelu_exact(s);
  }
  __syncthreads();
  if(t < GSIZE){
    float s = fb[256];
    for(int c = 0; c < DH; c++) s += ts[t][c] * fb[192 + c];
    scores[t] = s;
  }
  __syncthreads();
  if(t < GSIZE){
    float mx = -1e30f;
    for(int j = 0; j < GSIZE; j++) mx = fmaxf(mx, scores[j]);
    float sum = 0.f;
    for(int j = 0; j < GSIZE; j++) sum += __expf(scores[j] - mx);
    wsm[t] = __expf(scores[t] - mx) / (sum + 1e-16f);
  }
  __syncthreads();
  if(t < DIN){
    float s = 0.f;
    #pragma unroll 8
    for(int i = 0; i < GSIZE; i++) s += wsm[i] * x[(size_t)(base+i)*DIN + t];
    out[(size_t)blockIdx.x*DIN + t] = s;
  }
}

extern "C" void kernel_launch(void* const* d_in, const int* in_sizes, int n_in,
                              void* d_out, int out_size, void* d_ws, size_t ws_size,
                              hipStream_t stream){
  (void)in_sizes; (void)n_in; (void)out_size; (void)ws_size;
  const float* x    = (const float*)d_in[0];
  const float* nq_w = (const float*)d_in[4];
  const float* nq_b = (const float*)d_in[5];
  const float* nq_ms= (const float*)d_in[6];
  const float* wq   = (const float*)d_in[7];
  const float* bq   = (const float*)d_in[8];
  const float* wk   = (const float*)d_in[9];
  const float* bk   = (const float*)d_in[10];
  const float* wv   = (const float*)d_in[11];
  const float* bv   = (const float*)d_in[12];
  const float* no_w = (const float*)d_in[13];
  const float* no_b = (const float*)d_in[14];
  const float* no_ms= (const float*)d_in[15];
  const float* o_w1 = (const float*)d_in[16];
  const float* o_b1 = (const float*)d_in[17];
  const float* o_w2 = (const float*)d_in[18];
  const float* o_b2 = (const float*)d_in[19];
  const float* pn_w = (const float*)d_in[20];
  const float* pn_b = (const float*)d_in[21];
  const float* pn_ms= (const float*)d_in[22];
  const float* p_w1 = (const float*)d_in[23];
  const float* p_b1 = (const float*)d_in[24];
  const float* p_w2 = (const float*)d_in[25];
  const float* p_b2 = (const float*)d_in[26];

  float* ws = (float*)d_ws;
  float* hcomb = (float*)((char*)d_ws + HCOMB_BYTE);

  // zero the two atomic counter regions (poisoned 0xAA by harness)
  hipMemsetAsync((char*)d_ws + (size_t)XPCNT*4, 0, 1028, stream);
  k_pre<<<207, 256, 0, stream>>>(x, o_w1, o_w2, p_w1, o_b1, o_b2, p_b1, p_w2, p_b2,
                                 wq, wk, wv, nq_w, nq_b, nq_ms, ws);
  k_fused<<<1024, 256, 0, stream>>>(x, bq, bk, bv, ws, hcomb);
  k_final<<<NGRAPH, 256, 0, stream>>>(x, hcomb, ws, no_w, no_b, no_ms,
                                      pn_w, pn_b, pn_ms, (float*)d_out);
}

// Round 11
// 281.036 us; speedup vs baseline: 1.0567x; 1.0567x over previous
//
#include <hip/hip_runtime.h>
#include <stdint.h>

// FP32 in/out (R4). bf16 only for MFMA operands.
// R6: no cooperative mega-kernel. R8: union-array prefetch buffers spill.
// R10: __launch_bounds__(256,4) min-waves arg capped VGPR at 64 -> the
// 96-VGPR prefetch buffers spilled (116MB WRITE). Fix: no min-waves arg;
// natural occupancy (VGPR ~120-160 -> 3-4 blocks/CU) keeps buffers in regs.

#define N_NODES 6144
#define GSIZE 24
#define NGRAPH 256
#define DIN 128
#define DH 64
#define EFF 512
#define EPSN 1e-5f

typedef __attribute__((ext_vector_type(8))) __bf16 bf16x8;
typedef __attribute__((ext_vector_type(4))) float f32x4;
union U16B { uint4 u; bf16x8 v; unsigned short s[8]; };

__device__ inline float bf2f(unsigned short u){ return __uint_as_float(((unsigned)u)<<16); }
__device__ inline unsigned short f2bf(float f){
  unsigned u = __float_as_uint(f);
  u += 0x7fff + ((u>>16)&1);
  return (unsigned short)(u>>16);
}
__device__ inline float gelu_exact(float x){ return 0.5f*x*(1.0f+erff(x*0.70710678118654752f)); }

// ---- workspace float offsets ----
#define XP     0         // 192 x 256: x col stat partials
#define A1C1   49152     // 256 floats: norm1 coeffs (k_pre finisher)
#define HP     49408     // 256 x 128: h col stat partials
#define WT1    82176
#define WT2    86272
#define PWT1   90368
#define FBo    94464     // 257 floats
#define XPCNT  95232     // 1 int  (k_pre finisher counter)   byte 380928
#define CNT    95233     // 256 ints (k_fused combiner cnts)  ends byte 381956
#define WCVT_BYTE  382976    // 3 x 512 x 128 bf16 = 393216 B
#define HPART_BYTE 776192    // 1024 x 24 x 64 fp32 = 6291456 B
#define HCOMB_BYTE 7067648   // 6144 x 64 fp32

// ================= K1: k_pre =================
// blocks 0..191: x col-stat partials; last finisher computes A1/C1.
// blocks 192..194: transpose o_w1/o_w2/p_w1 (+bias staging in 192)
// blocks 195..206: wq/wk/wv -> bf16 (12 segments)
__global__ __launch_bounds__(256)
void k_pre(const float* __restrict__ x,
           const float* __restrict__ o_w1, const float* __restrict__ o_w2,
           const float* __restrict__ p_w1,
           const float* __restrict__ o_b1, const float* __restrict__ o_b2,
           const float* __restrict__ p_b1, const float* __restrict__ p_w2,
           const float* __restrict__ p_b2,
           const float* __restrict__ wq, const float* __restrict__ wk,
           const float* __restrict__ wv,
           const float* __restrict__ nq_w, const float* __restrict__ nq_b,
           const float* __restrict__ nq_ms,
           float* __restrict__ wsf){
  int t = threadIdx.x;
  int bi = blockIdx.x;
  if(bi < 192){
    int c = t & 127, h = t >> 7;
    float s = 0.f, q = 0.f;
    #pragma unroll
    for(int r = 0; r < 16; ++r){
      float v = x[(size_t)(bi*32 + h + 2*r)*DIN + c];
      s += v; q += v*v;
    }
    __shared__ float sm[256], sm2[256];
    __shared__ int lastf;
    sm[t] = s; sm2[t] = q;
    __syncthreads();
    if(t < 128){
      wsf[XP + bi*256 + t]       = sm[t] + sm[t+128];
      wsf[XP + bi*256 + 128 + t] = sm2[t] + sm2[t+128];
    }
    __syncthreads();                 // drain stores
    if(t == 0){
      __threadfence();
      int old = atomicAdd((int*)(wsf + XPCNT), 1);
      lastf = (old == 191);
    }
    __syncthreads();
    if(!lastf) return;
    __threadfence();
    // finisher: reduce 192 partials for idx=t (0..127 sums, 128..255 sumsq)
    float acc = 0.f;
    for(int p = 0; p < 192; ++p) acc += wsf[XP + p*256 + t];
    sm[t] = acc;
    __syncthreads();
    if(t < 128){
      float mean = sm[t] * (1.0f / N_NODES);
      float ex2  = sm[128+t] * (1.0f / N_NODES);
      float cm   = mean * nq_ms[t];
      float var  = ex2 - 2.f*cm*mean + cm*cm;
      float rstd = rsqrtf(var + EPSN);
      float a    = nq_w[t] * rstd;
      wsf[A1C1 + t]       = a;
      wsf[A1C1 + 128 + t] = nq_b[t] - a*cm;
    }
    return;
  }
  if(bi < 195){
    const float* src; float* dst;
    if(bi == 192){ src = o_w1; dst = wsf + WT1; }
    else if(bi == 193){ src = o_w2; dst = wsf + WT2; }
    else { src = p_w1; dst = wsf + PWT1; }
    for(int p = t; p < DH*DH; p += 256){
      int r = p >> 6, c = p & 63;
      dst[c*DH + r] = src[p];
    }
    if(bi == 192){
      float* fb = wsf + FBo;
      if(t < 64){
        fb[t]       = o_b1[t];
        fb[64 + t]  = o_b2[t];
        fb[128 + t] = p_b1[t];
        fb[192 + t] = p_w2[t];
      }
      if(t == 0) fb[256] = p_b2[0];
    }
    return;
  }
  int j = bi - 195;               // 0..11
  int mat = j >> 2, seg = j & 3;
  const float* src = (mat==0) ? wq : (mat==1) ? wk : wv;
  unsigned short* dst = (unsigned short*)((char*)wsf + WCVT_BYTE)
                        + (size_t)mat*EFF*DIN + seg*16384;
  const float* sp = src + seg*16384;
  for(int e = t*8; e < 16384; e += 2048){
    float4 a = *(const float4*)(sp + e);
    float4 b = *(const float4*)(sp + e + 4);
    U16B o;
    o.s[0]=f2bf(a.x); o.s[1]=f2bf(a.y); o.s[2]=f2bf(a.z); o.s[3]=f2bf(a.w);
    o.s[4]=f2bf(b.x); o.s[5]=f2bf(b.y); o.s[6]=f2bf(b.z); o.s[7]=f2bf(b.w);
    *(uint4*)(dst + e) = o.u;
  }
}

// ================= K2: k_fused =================
// 1024 blocks x 256 thr, 4 blocks per graph (2 heads each).
// NO min-waves in launch_bounds: let VGPRs stay ~120-160 (R10 lesson).
__global__ __launch_bounds__(256)
void k_fused(const float* __restrict__ x,
             const float* __restrict__ bq, const float* __restrict__ bk,
             const float* __restrict__ bv,
             float* __restrict__ ws, float* __restrict__ hcomb){
  __shared__ __align__(16) float hv[GSIZE][68];
  __shared__ float A1s[128], C1s[128];
  __shared__ __align__(16) float qs[GSIZE][68], ks[GSIZE][68], vs[GSIZE][68];
  __shared__ __align__(16) float S[GSIZE][28];
  __shared__ int lastf;

  int t = threadIdx.x, b = blockIdx.x;
  int g = b >> 2, quarter = b & 3, base = g * GSIZE;
  const unsigned short* wcvt = (const unsigned short*)((const char*)ws + WCVT_BYTE);
  float* hpart = (float*)((char*)ws + HPART_BYTE);

  if(t < 128){ A1s[t] = ws[A1C1 + t]; C1s[t] = ws[A1C1 + 128 + t]; }
  __syncthreads();

  int wv4 = t >> 6, lane = t & 63, m = lane & 15, quad = lane >> 4;
  int mt = wv4 & 1, cth = wv4 >> 1;
  int node = mt*16 + m;
  int xrow = base + ((node < GSIZE) ? node : 0);

  // normalized x fragments (B operand), reused both iters
  bf16x8 xfr[4];
  #pragma unroll
  for(int kk = 0; kk < 4; kk++){
    int k0 = kk*32 + quad*8;
    float4 a = *(const float4*)(x + (size_t)xrow*DIN + k0);
    float4 bfl = *(const float4*)(x + (size_t)xrow*DIN + k0 + 4);
    U16B u;
    u.s[0] = f2bf(a.x*A1s[k0+0] + C1s[k0+0]);
    u.s[1] = f2bf(a.y*A1s[k0+1] + C1s[k0+1]);
    u.s[2] = f2bf(a.z*A1s[k0+2] + C1s[k0+2]);
    u.s[3] = f2bf(a.w*A1s[k0+3] + C1s[k0+3]);
    u.s[4] = f2bf(bfl.x*A1s[k0+4] + C1s[k0+4]);
    u.s[5] = f2bf(bfl.y*A1s[k0+5] + C1s[k0+5]);
    u.s[6] = f2bf(bfl.z*A1s[k0+6] + C1s[k0+6]);
    u.s[7] = f2bf(bfl.w*A1s[k0+7] + C1s[k0+7]);
    xfr[kk] = u.v;
  }

  // POD prefetch buffers (R8 spill lesson)
  uint4 wbuf[6][4];
  float4 bb[6];
  {
    int hh = quarter*2;
    #pragma unroll
    for(int task = 0; task < 6; ++task){
      int tk = cth*6 + task;
      int mat = tk >> 2, ctm = tk & 3;
      const unsigned short* wp = wcvt + (size_t)mat*EFF*DIN
                               + (size_t)(hh*64 + ctm*16 + m)*DIN + quad*8;
      #pragma unroll
      for(int kk = 0; kk < 4; kk++) wbuf[task][kk] = *(const uint4*)(wp + kk*32);
      const float* bias = (mat==0) ? bq : (mat==1) ? bk : bv;
      bb[task] = *(const float4*)(bias + hh*64 + ctm*16 + quad*4);
    }
  }

  f32x4 a0 = {0.f,0.f,0.f,0.f}, a1 = {0.f,0.f,0.f,0.f};

  for(int iter = 0; iter < 2; ++iter){
    __syncthreads();                          // prior PV done; tiles reusable
    #pragma unroll
    for(int task = 0; task < 6; ++task){
      int tk = cth*6 + task;
      int mat = tk >> 2, ctm = tk & 3;
      f32x4 acc = {0.f,0.f,0.f,0.f};
      #pragma unroll
      for(int kk = 0; kk < 4; kk++){
        U16B w8; w8.u = wbuf[task][kk];
        acc = __builtin_amdgcn_mfma_f32_16x16x32_bf16(w8.v, xfr[kk], acc, 0, 0, 0);
      }
      float (*tile)[68] = (mat==0) ? qs : (mat==1) ? ks : vs;
      if(mt == 0 || m < 8){
        int d0 = ctm*16 + quad*4;
        tile[node][d0+0] = acc[0] + bb[task].x;
        tile[node][d0+1] = acc[1] + bb[task].y;
        tile[node][d0+2] = acc[2] + bb[task].z;
        tile[node][d0+3] = acc[3] + bb[task].w;
      }
    }
    __syncthreads();                          // tiles ready
    if(iter == 0){                            // prefetch 2nd head during S+PV
      int hh = quarter*2 + 1;
      #pragma unroll
      for(int task = 0; task < 6; ++task){
        int tk = cth*6 + task;
        int mat = tk >> 2, ctm = tk & 3;
        const unsigned short* wp = wcvt + (size_t)mat*EFF*DIN
                                 + (size_t)(hh*64 + ctm*16 + m)*DIN + quad*8;
        #pragma unroll
        for(int kk = 0; kk < 4; kk++) wbuf[task][kk] = *(const uint4*)(wp + kk*32);
        const float* bias = (mat==0) ? bq : (mat==1) ? bk : bv;
        bb[task] = *(const float4*)(bias + hh*64 + ctm*16 + quad*4);
      }
    }
    // ---- S + softmax fused ----
    if(t < 192){
      int row = t >> 3, sl = t & 7;
      const float4* qi = (const float4*)qs[row];
      const float4* k0p = (const float4*)ks[sl*3];
      const float4* k1p = (const float4*)ks[sl*3+1];
      const float4* k2p = (const float4*)ks[sl*3+2];
      float s0 = 0.f, s1 = 0.f, s2 = 0.f;
      #pragma unroll
      for(int d = 0; d < 16; ++d){
        float4 qv = qi[d];
        float4 ka = k0p[d], kb = k1p[d], kc = k2p[d];
        s0 += qv.x*ka.x + qv.y*ka.y + qv.z*ka.z + qv.w*ka.w;
        s1 += qv.x*kb.x + qv.y*kb.y + qv.z*kb.z + qv.w*kb.w;
        s2 += qv.x*kc.x + qv.y*kc.y + qv.z*kc.z + qv.w*kc.w;
      }
      s0 *= 0.125f; s1 *= 0.125f; s2 *= 0.125f;
      float m0 = fmaxf(fmaxf(s0, s1), s2);
      #pragma unroll
      for(int o = 1; o < 8; o <<= 1) m0 = fmaxf(m0, __shfl_xor(m0, o, 8));
      float e0 = __expf(s0-m0), e1 = __expf(s1-m0), e2 = __expf(s2-m0);
      float su = e0 + e1 + e2;
      #pragma unroll
      for(int o = 1; o < 8; o <<= 1) su += __shfl_xor(su, o, 8);
      float inv = 1.0f / (su + 1e-16f);
      S[row][sl*3]   = e0*inv;
      S[row][sl*3+1] = e1*inv;
      S[row][sl*3+2] = e2*inv;
    }
    __syncthreads();
    // ---- PV accumulate ----
    {
      int i = t >> 4, dq = t & 15;
      #pragma unroll 8
      for(int j = 0; j < GSIZE; ++j){
        float w = S[i][j];
        float4 v = *(const float4*)&vs[j][dq*4];
        a0.x += w*v.x; a0.y += w*v.y; a0.z += w*v.z; a0.w += w*v.w;
      }
      if(t < 128){
        int p = t + 256; int i2 = p >> 4, dq2 = p & 15;
        #pragma unroll 8
        for(int j = 0; j < GSIZE; ++j){
          float w = S[i2][j];
          float4 v = *(const float4*)&vs[j][dq2*4];
          a1.x += w*v.x; a1.y += w*v.y; a1.z += w*v.z; a1.w += w*v.w;
        }
      }
    }
  }
  __syncthreads();
  // ---- write 2-head partial (mean weight 1/8 per head) ----
  {
    int i = t >> 4, dq = t & 15;
    float4 o; o.x = a0.x*0.125f; o.y = a0.y*0.125f; o.z = a0.z*0.125f; o.w = a0.w*0.125f;
    if(quarter == 0){
      const float* xr = x + (size_t)(base+i)*DIN + dq*4;
      float4 r1 = *(const float4*)xr;
      float4 r2 = *(const float4*)(xr + 64);
      o.x += r1.x + r2.x; o.y += r1.y + r2.y; o.z += r1.z + r2.z; o.w += r1.w + r2.w;
    }
    *(float4*)&hv[i][dq*4] = o;
    *(float4*)(hpart + ((size_t)b*GSIZE + i)*DH + dq*4) = o;
    if(t < 128){
      int p = t + 256; int i2 = p >> 4, dq2 = p & 15;
      float4 o2; o2.x = a1.x*0.125f; o2.y = a1.y*0.125f; o2.z = a1.z*0.125f; o2.w = a1.w*0.125f;
      if(quarter == 0){
        const float* xr = x + (size_t)(base+i2)*DIN + dq2*4;
        float4 r1 = *(const float4*)xr;
        float4 r2 = *(const float4*)(xr + 64);
        o2.x += r1.x + r2.x; o2.y += r1.y + r2.y; o2.z += r1.z + r2.z; o2.w += r1.w + r2.w;
      }
      *(float4*)&hv[i2][dq2*4] = o2;
      *(float4*)(hpart + ((size_t)b*GSIZE + i2)*DH + dq2*4) = o2;
    }
  }
  __syncthreads();                 // drain partial stores
  if(t == 0){
    __threadfence();
    int old = atomicAdd((int*)(ws + CNT) + g, 1);
    lastf = (old == 3);
  }
  __syncthreads();
  if(!lastf) return;
  __threadfence();                 // acquire: see peers' partials
  {
    int gb = g << 2;
    int i = t >> 4, dq = t & 15;
    float4 o = *(float4*)&hv[i][dq*4];
    #pragma unroll
    for(int qq = 0; qq < 4; ++qq){
      if(qq == quarter) continue;
      float4 pv = *(const float4*)(hpart + ((size_t)(gb+qq)*GSIZE + i)*DH + dq*4);
      o.x += pv.x; o.y += pv.y; o.z += pv.z; o.w += pv.w;
    }
    *(float4*)&hv[i][dq*4] = o;
    *(float4*)(hcomb + (size_t)(base+i)*DH + dq*4) = o;
    if(t < 128){
      int p = t + 256; int i2 = p >> 4, dq2 = p & 15;
      float4 o2 = *(float4*)&hv[i2][dq2*4];
      #pragma unroll
      for(int qq = 0; qq < 4; ++qq){
        if(qq == quarter) continue;
        float4 pv = *(const float4*)(hpart + ((size_t)(gb+qq)*GSIZE + i2)*DH + dq2*4);
        o2.x += pv.x; o2.y += pv.y; o2.z += pv.z; o2.w += pv.w;
      }
      *(float4*)&hv[i2][dq2*4] = o2;
      *(float4*)(hcomb + (size_t)(base+i2)*DH + dq2*4) = o2;
    }
  }
  __syncthreads();
  if(t < 64){
    float s1 = 0.f, s2 = 0.f;
    #pragma unroll
    for(int i = 0; i < GSIZE; ++i){ float v = hv[i][t]; s1 += v; s2 += v*v; }
    ws[HP + g*128 + t]      = s1;
    ws[HP + g*128 + 64 + t] = s2;
  }
}

// ================= K3: k_final =================
__global__ __launch_bounds__(256)
void k_final(const float* __restrict__ x,
             const float* __restrict__ hbuf, const float* __restrict__ ws,
             const float* __restrict__ no_w, const float* __restrict__ no_b,
             const float* __restrict__ no_ms,
             const float* __restrict__ pn_w, const float* __restrict__ pn_b,
             const float* __restrict__ pn_ms,
             float* __restrict__ out){
  const float* pwt1 = ws + PWT1;
  const float* fb   = ws + FBo;

  __shared__ float wt1s[64][64], wt2s[64][64];   // 32 KB staged weights
  __shared__ float hs[GSIZE][DH];
  __shared__ float hn[GSIZE][DH];
  __shared__ float ts[GSIZE][DH];
  __shared__ float A2[DH], C2[DH];
  __shared__ float a3[DH], c3[DH];
  __shared__ float scores[GSIZE], wsm[GSIZE];
  __shared__ float redA[256], redB[256];

  int t = threadIdx.x;
  int base = blockIdx.x * GSIZE;

  for(int p = t; p < DH*DH; p += 256){
    wt1s[p>>6][p&63] = ws[WT1 + p];
    wt2s[p>>6][p&63] = ws[WT2 + p];
  }
  {
    int c = t & 63, grp = t >> 6;
    float s1 = 0.f, s2 = 0.f;
    for(int p = grp; p < NGRAPH; p += 4){
      s1 += ws[HP + p*128 + c];
      s2 += ws[HP + p*128 + 64 + c];
    }
    redA[t] = s1; redB[t] = s2;
  }
  __syncthreads();
  if(t < DH){
    float s1 = redA[t] + redA[t+64] + redA[t+128] + redA[t+192];
    float s2 = redB[t] + redB[t+64] + redB[t+128] + redB[t+192];
    float mean = s1 * (1.0f / N_NODES);
    float ex2  = s2 * (1.0f / N_NODES);
    float cm   = mean * no_ms[t];
    float var  = ex2 - 2.f*cm*mean + cm*cm;
    float rstd = rsqrtf(var + EPSN);
    float a    = no_w[t] * rstd;
    A2[t] = a; C2[t] = no_b[t] - a*cm;
  }
  __syncthreads();
  for(int p = t; p < GSIZE*DH; p += 256){
    int i = p >> 6, d = p & 63;
    float hvv = hbuf[(size_t)(base+i)*DH + d];
    hs[i][d] = hvv;
    hn[i][d] = A2[d]*hvv + C2[d];
  }
  __syncthreads();
  for(int p = t; p < GSIZE*DH; p += 256){
    int i = p >> 6, c = p & 63;
    float s = fb[c];
    #pragma unroll
    for(int k = 0; k < DH; k++) s += hn[i][k] * wt1s[k][c];
    ts[i][c] = gelu_exact(s);
  }
  __syncthreads();
  for(int p = t; p < GSIZE*DH; p += 256){
    int i = p >> 6, c = p & 63;
    float s = fb[64 + c];
    #pragma unroll
    for(int k = 0; k < DH; k++) s += ts[i][k] * wt2s[k][c];
    hs[i][c] = hs[i][c] + s;
  }
  __syncthreads();
  if(t < DH){
    float s1 = 0.f, s2 = 0.f;
    for(int i = 0; i < GSIZE; i++){ float v = hs[i][t]; s1 += v; s2 += v*v; }
    float mean = s1 * (1.0f / GSIZE);
    float ex2  = s2 * (1.0f / GSIZE);
    float cm   = mean * pn_ms[t];
    float var  = ex2 - 2.f*cm*mean + cm*cm;
    float rstd = rsqrtf(var + EPSN);
    float a    = pn_w[t] * rstd;
    a3[t] = a; c3[t] = pn_b[t] - a*cm;
  }
  __syncthreads();
  for(int p = t; p < GSIZE*DH; p += 256){
    int i = p >> 6, d = p & 63;
    hn[i][d] = a3[d]*hs[i][d] + c3[d];
  }
  __syncthreads();
  for(int p = t; p < GSIZE*DH; p += 256){
    int i = p >> 6, c = p & 63;
    float s = fb[128 + c];
    #pragma unroll
    for(int k = 0; k < DH; k++) s += hn[i][k] * pwt1[k*DH + c];
    ts[i][c] = gelu_exact(s);
  }
  __syncthreads();
  if(t < GSIZE){
    float s = fb[256];
    for(int c = 0; c < DH; c++) s += ts[t][c] * fb[192 + c];
    scores[t] = s;
  }
  __syncthreads();
  if(t < GSIZE){
    float mx = -1e30f;
    for(int j = 0; j < GSIZE; j++) mx = fmaxf(mx, scores[j]);
    float sum = 0.f;
    for(int j = 0; j < GSIZE; j++) sum += __expf(scores[j] - mx);
    wsm[t] = __expf(scores[t] - mx) / (sum + 1e-16f);
  }
  __syncthreads();
  if(t < DIN){
    float s = 0.f;
    #pragma unroll 8
    for(int i = 0; i < GSIZE; i++) s += wsm[i] * x[(size_t)(base+i)*DIN + t];
    out[(size_t)blockIdx.x*DIN + t] = s;
  }
}

extern "C" void kernel_launch(void* const* d_in, const int* in_sizes, int n_in,
                              void* d_out, int out_size, void* d_ws, size_t ws_size,
                              hipStream_t stream){
  (void)in_sizes; (void)n_in; (void)out_size; (void)ws_size;
  const float* x    = (const float*)d_in[0];
  const float* nq_w = (const float*)d_in[4];
  const float* nq_b = (const float*)d_in[5];
  const float* nq_ms= (const float*)d_in[6];
  const float* wq   = (const float*)d_in[7];
  const float* bq   = (const float*)d_in[8];
  const float* wk   = (const float*)d_in[9];
  const float* bk   = (const float*)d_in[10];
  const float* wv   = (const float*)d_in[11];
  const float* bv   = (const float*)d_in[12];
  const float* no_w = (const float*)d_in[13];
  const float* no_b = (const float*)d_in[14];
  const float* no_ms= (const float*)d_in[15];
  const float* o_w1 = (const float*)d_in[16];
  const float* o_b1 = (const float*)d_in[17];
  const float* o_w2 = (const float*)d_in[18];
  const float* o_b2 = (const float*)d_in[19];
  const float* pn_w = (const float*)d_in[20];
  const float* pn_b = (const float*)d_in[21];
  const float* pn_ms= (const float*)d_in[22];
  const float* p_w1 = (const float*)d_in[23];
  const float* p_b1 = (const float*)d_in[24];
  const float* p_w2 = (const float*)d_in[25];
  const float* p_b2 = (const float*)d_in[26];

  float* ws = (float*)d_ws;
  float* hcomb = (float*)((char*)d_ws + HCOMB_BYTE);

  // zero the two atomic counter regions (poisoned 0xAA by harness)
  hipMemsetAsync((char*)d_ws + (size_t)XPCNT*4, 0, 1028, stream);
  k_pre<<<207, 256, 0, stream>>>(x, o_w1, o_w2, p_w1, o_b1, o_b2, p_b1, p_w2, p_b2,
                                 wq, wk, wv, nq_w, nq_b, nq_ms, ws);
  k_fused<<<1024, 256, 0, stream>>>(x, bq, bk, bv, ws, hcomb);
  k_final<<<NGRAPH, 256, 0, stream>>>(x, hcomb, ws, no_w, no_b, no_ms,
                                      pn_w, pn_b, pn_ms, (float*)d_out);
}

// Round 12
// 231.633 us; speedup vs baseline: 1.2820x; 1.2133x over previous
//
#include <hip/hip_runtime.h>
#include <stdint.h>

// FP32 in/out (R4). bf16 only for MFMA operands.
// Lessons: R6 no cooperative mega-kernel; R8 union-array prefetch spills;
// R10 launch_bounds min-waves caps VGPR -> spill; R10/R11 4-block/graph
// split regresses (weight re-reads scale, per-block latency ~30us is
// structural). R12: R9 shape (256 blocks x 512 thr) + wave-synchronous
// S/softmax/PV (barriers per iter 3->2, no cross-wave S handoff).

#define N_NODES 6144
#define GSIZE 24
#define NGRAPH 256
#define DIN 128
#define DH 64
#define EFF 512
#define EPSN 1e-5f

typedef __attribute__((ext_vector_type(8))) __bf16 bf16x8;
typedef __attribute__((ext_vector_type(4))) float f32x4;
union U16B { uint4 u; bf16x8 v; unsigned short s[8]; };

__device__ inline float bf2f(unsigned short u){ return __uint_as_float(((unsigned)u)<<16); }
__device__ inline unsigned short f2bf(float f){
  unsigned u = __float_as_uint(f);
  u += 0x7fff + ((u>>16)&1);
  return (unsigned short)(u>>16);
}
__device__ inline float gelu_exact(float x){ return 0.5f*x*(1.0f+erff(x*0.70710678118654752f)); }

// ---- workspace float offsets ----
#define XP     0         // 192 x 256: x col stat partials
#define A1C1   49152     // 256 floats: norm1 coeffs (k_pre finisher)
#define HP     49408     // 256 x 128: h col stat partials
#define WT1    82176
#define WT2    86272
#define PWT1   90368
#define FBo    94464     // 257 floats
#define XPCNT  95232     // 1 int (k_pre finisher counter) at byte 380928
#define WCVT_BYTE  382976    // 3 x 512 x 128 bf16
#define HCOMB_BYTE 7067648   // 6144 x 64 fp32

// ================= K1: k_pre =================
__global__ __launch_bounds__(256)
void k_pre(const float* __restrict__ x,
           const float* __restrict__ o_w1, const float* __restrict__ o_w2,
           const float* __restrict__ p_w1,
           const float* __restrict__ o_b1, const float* __restrict__ o_b2,
           const float* __restrict__ p_b1, const float* __restrict__ p_w2,
           const float* __restrict__ p_b2,
           const float* __restrict__ wq, const float* __restrict__ wk,
           const float* __restrict__ wv,
           const float* __restrict__ nq_w, const float* __restrict__ nq_b,
           const float* __restrict__ nq_ms,
           float* __restrict__ wsf){
  int t = threadIdx.x;
  int bi = blockIdx.x;
  if(bi < 192){
    int c = t & 127, h = t >> 7;
    float s = 0.f, q = 0.f;
    #pragma unroll
    for(int r = 0; r < 16; ++r){
      float v = x[(size_t)(bi*32 + h + 2*r)*DIN + c];
      s += v; q += v*v;
    }
    __shared__ float sm[256], sm2[256];
    __shared__ int lastf;
    sm[t] = s; sm2[t] = q;
    __syncthreads();
    if(t < 128){
      wsf[XP + bi*256 + t]       = sm[t] + sm[t+128];
      wsf[XP + bi*256 + 128 + t] = sm2[t] + sm2[t+128];
    }
    __syncthreads();
    if(t == 0){
      __threadfence();
      int old = atomicAdd((int*)(wsf + XPCNT), 1);
      lastf = (old == 191);
    }
    __syncthreads();
    if(!lastf) return;
    __threadfence();
    float acc = 0.f;
    for(int p = 0; p < 192; ++p) acc += wsf[XP + p*256 + t];
    sm[t] = acc;
    __syncthreads();
    if(t < 128){
      float mean = sm[t] * (1.0f / N_NODES);
      float ex2  = sm[128+t] * (1.0f / N_NODES);
      float cm   = mean * nq_ms[t];
      float var  = ex2 - 2.f*cm*mean + cm*cm;
      float rstd = rsqrtf(var + EPSN);
      float a    = nq_w[t] * rstd;
      wsf[A1C1 + t]       = a;
      wsf[A1C1 + 128 + t] = nq_b[t] - a*cm;
    }
    return;
  }
  if(bi < 195){
    const float* src; float* dst;
    if(bi == 192){ src = o_w1; dst = wsf + WT1; }
    else if(bi == 193){ src = o_w2; dst = wsf + WT2; }
    else { src = p_w1; dst = wsf + PWT1; }
    for(int p = t; p < DH*DH; p += 256){
      int r = p >> 6, c = p & 63;
      dst[c*DH + r] = src[p];
    }
    if(bi == 192){
      float* fb = wsf + FBo;
      if(t < 64){
        fb[t]       = o_b1[t];
        fb[64 + t]  = o_b2[t];
        fb[128 + t] = p_b1[t];
        fb[192 + t] = p_w2[t];
      }
      if(t == 0) fb[256] = p_b2[0];
    }
    return;
  }
  int j = bi - 195;
  int mat = j >> 2, seg = j & 3;
  const float* src = (mat==0) ? wq : (mat==1) ? wk : wv;
  unsigned short* dst = (unsigned short*)((char*)wsf + WCVT_BYTE)
                        + (size_t)mat*EFF*DIN + seg*16384;
  const float* sp = src + seg*16384;
  for(int e = t*8; e < 16384; e += 2048){
    float4 a = *(const float4*)(sp + e);
    float4 b = *(const float4*)(sp + e + 4);
    U16B o;
    o.s[0]=f2bf(a.x); o.s[1]=f2bf(a.y); o.s[2]=f2bf(a.z); o.s[3]=f2bf(a.w);
    o.s[4]=f2bf(b.x); o.s[5]=f2bf(b.y); o.s[6]=f2bf(b.z); o.s[7]=f2bf(b.w);
    *(uint4*)(dst + e) = o.u;
  }
}

// ================= K2: k_fused =================
// 256 blocks x 512 thr, 2 head-pipes x 4 iters. Wave-synchronous
// S/softmax/PV (each 16-lane group owns one S row; wave-local LDS).
__global__ __launch_bounds__(512)
void k_fused(const float* __restrict__ x,
             const float* __restrict__ bq, const float* __restrict__ bk,
             const float* __restrict__ bv,
             float* __restrict__ ws, float* __restrict__ hcomb){
  __shared__ __align__(16) float hv[GSIZE][68];
  __shared__ float A1s[128], C1s[128];
  __shared__ __align__(16) float qs[2][GSIZE][68], ks[2][GSIZE][68], vs[2][GSIZE][68];
  __shared__ __align__(16) float S[2][GSIZE][28];

  int t = threadIdx.x, g = blockIdx.x, base = g * GSIZE;
  const unsigned short* wcvt = (const unsigned short*)((const char*)ws + WCVT_BYTE);

  if(t < 128){ A1s[t] = ws[A1C1 + t]; C1s[t] = ws[A1C1 + 128 + t]; }
  __syncthreads();

  int pipe = t >> 8, t2 = t & 255;
  int wv4 = (t >> 6) & 3, lane = t & 63, m = lane & 15, quad = lane >> 4;
  int mt = wv4 & 1, cth = wv4 >> 1;
  int node = mt*16 + m;
  int xrow = base + ((node < GSIZE) ? node : 0);

  bf16x8 xfr[4];
  #pragma unroll
  for(int kk = 0; kk < 4; kk++){
    int k0 = kk*32 + quad*8;
    float4 a = *(const float4*)(x + (size_t)xrow*DIN + k0);
    float4 bfl = *(const float4*)(x + (size_t)xrow*DIN + k0 + 4);
    U16B u;
    u.s[0] = f2bf(a.x*A1s[k0+0] + C1s[k0+0]);
    u.s[1] = f2bf(a.y*A1s[k0+1] + C1s[k0+1]);
    u.s[2] = f2bf(a.z*A1s[k0+2] + C1s[k0+2]);
    u.s[3] = f2bf(a.w*A1s[k0+3] + C1s[k0+3]);
    u.s[4] = f2bf(bfl.x*A1s[k0+4] + C1s[k0+4]);
    u.s[5] = f2bf(bfl.y*A1s[k0+5] + C1s[k0+5]);
    u.s[6] = f2bf(bfl.z*A1s[k0+6] + C1s[k0+6]);
    u.s[7] = f2bf(bfl.w*A1s[k0+7] + C1s[k0+7]);
    xfr[kk] = u.v;
  }

  // POD prefetch buffers (R8 lesson); prologue loads head = pipe
  uint4 wbuf[6][4];
  float4 bb[6];
  {
    int hh = pipe;
    #pragma unroll
    for(int task = 0; task < 6; ++task){
      int tk = cth*6 + task;
      int mat = tk >> 2, ctm = tk & 3;
      const unsigned short* wp = wcvt + (size_t)mat*EFF*DIN
                               + (size_t)(hh*64 + ctm*16 + m)*DIN + quad*8;
      #pragma unroll
      for(int kk = 0; kk < 4; kk++) wbuf[task][kk] = *(const uint4*)(wp + kk*32);
      const float* bias = (mat==0) ? bq : (mat==1) ? bk : bv;
      bb[task] = *(const float4*)(bias + hh*64 + ctm*16 + quad*4);
    }
  }

  f32x4 a0 = {0.f,0.f,0.f,0.f}, a1 = {0.f,0.f,0.f,0.f};
  int i0 = t2 >> 4, dq0 = t2 & 15;       // slot0: rows 0..15
  int i1 = 16 + (t2 >> 4), dq1 = t2 & 15; // slot1 (t2<128): rows 16..23

  for(int iter = 0; iter < 4; ++iter){
    __syncthreads();                      // prior PV done; tiles reusable
    #pragma unroll
    for(int task = 0; task < 6; ++task){
      int tk = cth*6 + task;
      int mat = tk >> 2, ctm = tk & 3;
      f32x4 acc = {0.f,0.f,0.f,0.f};
      #pragma unroll
      for(int kk = 0; kk < 4; kk++){
        U16B w8; w8.u = wbuf[task][kk];
        acc = __builtin_amdgcn_mfma_f32_16x16x32_bf16(w8.v, xfr[kk], acc, 0, 0, 0);
      }
      float (*tile)[68] = (mat==0) ? qs[pipe] : (mat==1) ? ks[pipe] : vs[pipe];
      if(mt == 0 || m < 8){
        int d0 = ctm*16 + quad*4;
        tile[node][d0+0] = acc[0] + bb[task].x;
        tile[node][d0+1] = acc[1] + bb[task].y;
        tile[node][d0+2] = acc[2] + bb[task].z;
        tile[node][d0+3] = acc[3] + bb[task].w;
      }
    }
    __syncthreads();                      // tiles ready
    if(iter < 3){                         // prefetch next head during S+PV
      int hh = (iter+1)*2 + pipe;
      #pragma unroll
      for(int task = 0; task < 6; ++task){
        int tk = cth*6 + task;
        int mat = tk >> 2, ctm = tk & 3;
        const unsigned short* wp = wcvt + (size_t)mat*EFF*DIN
                                 + (size_t)(hh*64 + ctm*16 + m)*DIN + quad*8;
        #pragma unroll
        for(int kk = 0; kk < 4; kk++) wbuf[task][kk] = *(const uint4*)(wp + kk*32);
        const float* bias = (mat==0) ? bq : (mat==1) ? bk : bv;
        bb[task] = *(const float4*)(bias + hh*64 + ctm*16 + quad*4);
      }
    }
    // ---- wave-synchronous S + softmax (slot0: all, slot1: t2<128) ----
    {
      const float4* qi = (const float4*)qs[pipe][i0];
      const float4* ka = (const float4*)ks[pipe][dq0];
      float s0 = 0.f, s1 = -3.0e38f;
      #pragma unroll
      for(int d = 0; d < 16; ++d){
        float4 qv = qi[d], kv = ka[d];
        s0 += qv.x*kv.x + qv.y*kv.y + qv.z*kv.z + qv.w*kv.w;
      }
      s0 *= 0.125f;
      if(dq0 < 8){
        const float4* kb = (const float4*)ks[pipe][dq0+16];
        float sb = 0.f;
        #pragma unroll
        for(int d = 0; d < 16; ++d){
          float4 qv = qi[d], kv = kb[d];
          sb += qv.x*kv.x + qv.y*kv.y + qv.z*kv.z + qv.w*kv.w;
        }
        s1 = sb * 0.125f;
      }
      float mx = fmaxf(s0, s1);
      #pragma unroll
      for(int o = 1; o < 16; o <<= 1) mx = fmaxf(mx, __shfl_xor(mx, o, 16));
      float e0 = __expf(s0 - mx);
      float e1 = (dq0 < 8) ? __expf(s1 - mx) : 0.f;
      float su = e0 + e1;
      #pragma unroll
      for(int o = 1; o < 16; o <<= 1) su += __shfl_xor(su, o, 16);
      float inv = 1.0f / (su + 1e-16f);
      S[pipe][i0][dq0] = e0 * inv;
      if(dq0 < 8) S[pipe][i0][dq0+16] = e1 * inv;
    }
    if(t2 < 128){
      const float4* qi = (const float4*)qs[pipe][i1];
      const float4* ka = (const float4*)ks[pipe][dq1];
      float s0 = 0.f, s1 = -3.0e38f;
      #pragma unroll
      for(int d = 0; d < 16; ++d){
        float4 qv = qi[d], kv = ka[d];
        s0 += qv.x*kv.x + qv.y*kv.y + qv.z*kv.z + qv.w*kv.w;
      }
      s0 *= 0.125f;
      if(dq1 < 8){
        const float4* kb = (const float4*)ks[pipe][dq1+16];
        float sb = 0.f;
        #pragma unroll
        for(int d = 0; d < 16; ++d){
          float4 qv = qi[d], kv = kb[d];
          sb += qv.x*kv.x + qv.y*kv.y + qv.z*kv.z + qv.w*kv.w;
        }
        s1 = sb * 0.125f;
      }
      float mx = fmaxf(s0, s1);
      #pragma unroll
      for(int o = 1; o < 16; o <<= 1) mx = fmaxf(mx, __shfl_xor(mx, o, 16));
      float e0 = __expf(s0 - mx);
      float e1 = (dq1 < 8) ? __expf(s1 - mx) : 0.f;
      float su = e0 + e1;
      #pragma unroll
      for(int o = 1; o < 16; o <<= 1) su += __shfl_xor(su, o, 16);
      float inv = 1.0f / (su + 1e-16f);
      S[pipe][i1][dq1] = e0 * inv;
      if(dq1 < 8) S[pipe][i1][dq1+16] = e1 * inv;
    }
    // ---- PV (same wave wrote this row's S; DS in-order per wave) ----
    {
      #pragma unroll 8
      for(int j = 0; j < GSIZE; ++j){
        float w = S[pipe][i0][j];
        float4 v = *(const float4*)&vs[pipe][j][dq0*4];
        a0.x += w*v.x; a0.y += w*v.y; a0.z += w*v.z; a0.w += w*v.w;
      }
      if(t2 < 128){
        #pragma unroll 8
        for(int j = 0; j < GSIZE; ++j){
          float w = S[pipe][i1][j];
          float4 v = *(const float4*)&vs[pipe][j][dq1*4];
          a1.x += w*v.x; a1.y += w*v.y; a1.z += w*v.z; a1.w += w*v.w;
        }
      }
    }
  }
  __syncthreads();
  if(pipe == 1){
    {
      float4 o; o.x = a0.x*0.125f; o.y = a0.y*0.125f; o.z = a0.z*0.125f; o.w = a0.w*0.125f;
      *(float4*)&hv[i0][dq0*4] = o;
    }
    if(t2 < 128){
      float4 o; o.x = a1.x*0.125f; o.y = a1.y*0.125f; o.z = a1.z*0.125f; o.w = a1.w*0.125f;
      *(float4*)&hv[i1][dq1*4] = o;
    }
  }
  __syncthreads();
  if(pipe == 0){
    {
      float4 hp = *(const float4*)&hv[i0][dq0*4];
      const float* xr = x + (size_t)(base+i0)*DIN + dq0*4;
      float4 r1 = *(const float4*)xr;
      float4 r2 = *(const float4*)(xr + 64);
      float4 o;
      o.x = a0.x*0.125f + hp.x + r1.x + r2.x;
      o.y = a0.y*0.125f + hp.y + r1.y + r2.y;
      o.z = a0.z*0.125f + hp.z + r1.z + r2.z;
      o.w = a0.w*0.125f + hp.w + r1.w + r2.w;
      *(float4*)&hv[i0][dq0*4] = o;
      *(float4*)(hcomb + (size_t)(base+i0)*DH + dq0*4) = o;
    }
    if(t2 < 128){
      float4 hp = *(const float4*)&hv[i1][dq1*4];
      const float* xr = x + (size_t)(base+i1)*DIN + dq1*4;
      float4 r1 = *(const float4*)xr;
      float4 r2 = *(const float4*)(xr + 64);
      float4 o;
      o.x = a1.x*0.125f + hp.x + r1.x + r2.x;
      o.y = a1.y*0.125f + hp.y + r1.y + r2.y;
      o.z = a1.z*0.125f + hp.z + r1.z + r2.z;
      o.w = a1.w*0.125f + hp.w + r1.w + r2.w;
      *(float4*)&hv[i1][dq1*4] = o;
      *(float4*)(hcomb + (size_t)(base+i1)*DH + dq1*4) = o;
    }
  }
  __syncthreads();
  if(t < 64){
    float s1 = 0.f, s2 = 0.f;
    #pragma unroll
    for(int i = 0; i < GSIZE; ++i){ float v = hv[i][t]; s1 += v; s2 += v*v; }
    ws[HP + g*128 + t]      = s1;
    ws[HP + g*128 + 64 + t] = s2;
  }
}

// ================= K3: k_final =================
__global__ __launch_bounds__(256)
void k_final(const float* __restrict__ x,
             const float* __restrict__ hbuf, const float* __restrict__ ws,
             const float* __restrict__ no_w, const float* __restrict__ no_b,
             const float* __restrict__ no_ms,
             const float* __restrict__ pn_w, const float* __restrict__ pn_b,
             const float* __restrict__ pn_ms,
             float* __restrict__ out){
  const float* pwt1 = ws + PWT1;
  const float* fb   = ws + FBo;

  __shared__ float wt1s[64][64], wt2s[64][64];
  __shared__ float hs[GSIZE][DH];
  __shared__ float hn[GSIZE][DH];
  __shared__ float ts[GSIZE][DH];
  __shared__ float A2[DH], C2[DH];
  __shared__ float a3[DH], c3[DH];
  __shared__ float scores[GSIZE], wsm[GSIZE];
  __shared__ float redA[256], redB[256];

  int t = threadIdx.x;
  int base = blockIdx.x * GSIZE;

  for(int p = t; p < DH*DH; p += 256){
    wt1s[p>>6][p&63] = ws[WT1 + p];
    wt2s[p>>6][p&63] = ws[WT2 + p];
  }
  {
    int c = t & 63, grp = t >> 6;
    float s1 = 0.f, s2 = 0.f;
    for(int p = grp; p < NGRAPH; p += 4){
      s1 += ws[HP + p*128 + c];
      s2 += ws[HP + p*128 + 64 + c];
    }
    redA[t] = s1; redB[t] = s2;
  }
  __syncthreads();
  if(t < DH){
    float s1 = redA[t] + redA[t+64] + redA[t+128] + redA[t+192];
    float s2 = redB[t] + redB[t+64] + redB[t+128] + redB[t+192];
    float mean = s1 * (1.0f / N_NODES);
    float ex2  = s2 * (1.0f / N_NODES);
    float cm   = mean * no_ms[t];
    float var  = ex2 - 2.f*cm*mean + cm*cm;
    float rstd = rsqrtf(var + EPSN);
    float a    = no_w[t] * rstd;
    A2[t] = a; C2[t] = no_b[t] - a*cm;
  }
  __syncthreads();
  for(int p = t; p < GSIZE*DH; p += 256){
    int i = p >> 6, d = p & 63;
    float hvv = hbuf[(size_t)(base+i)*DH + d];
    hs[i][d] = hvv;
    hn[i][d] = A2[d]*hvv + C2[d];
  }
  __syncthreads();
  for(int p = t; p < GSIZE*DH; p += 256){
    int i = p >> 6, c = p & 63;
    float s = fb[c];
    #pragma unroll
    for(int k = 0; k < DH; k++) s += hn[i][k] * wt1s[k][c];
    ts[i][c] = gelu_exact(s);
  }
  __syncthreads();
  for(int p = t; p < GSIZE*DH; p += 256){
    int i = p >> 6, c = p & 63;
    float s = fb[64 + c];
    #pragma unroll
    for(int k = 0; k < DH; k++) s += ts[i][k] * wt2s[k][c];
    hs[i][c] = hs[i][c] + s;
  }
  __syncthreads();
  if(t < DH){
    float s1 = 0.f, s2 = 0.f;
    for(int i = 0; i < GSIZE; i++){ float v = hs[i][t]; s1 += v; s2 += v*v; }
    float mean = s1 * (1.0f / GSIZE);
    float ex2  = s2 * (1.0f / GSIZE);
    float cm   = mean * pn_ms[t];
    float var  = ex2 - 2.f*cm*mean + cm*cm;
    float rstd = rsqrtf(var + EPSN);
    float a    = pn_w[t] * rstd;
    a3[t] = a; c3[t] = pn_b[t] - a*cm;
  }
  __syncthreads();
  for(int p = t; p < GSIZE*DH; p += 256){
    int i = p >> 6, d = p & 63;
    hn[i][d] = a3[d]*hs[i][d] + c3[d];
  }
  __syncthreads();
  for(int p = t; p < GSIZE*DH; p += 256){
    int i = p >> 6, c = p & 63;
    float s = fb[128 + c];
    #pragma unroll
    for(int k = 0; k < DH; k++) s += hn[i][k] * pwt1[k*DH + c];
    ts[i][c] = gelu_exact(s);
  }
  __syncthreads();
  if(t < GSIZE){
    float s = fb[256];
    for(int c = 0; c < DH; c++) s += ts[t][c] * fb[192 + c];
    scores[t] = s;
  }
  __syncthreads();
  if(t < GSIZE){
    float mx = -1e30f;
    for(int j = 0; j < GSIZE; j++) mx = fmaxf(mx, scores[j]);
    float sum = 0.f;
    for(int j = 0; j < GSIZE; j++) sum += __expf(scores[j] - mx);
    wsm[t] = __expf(scores[t] - mx) / (sum + 1e-16f);
  }
  __syncthreads();
  if(t < DIN){
    float s = 0.f;
    #pragma unroll 8
    for(int i = 0; i < GSIZE; i++) s += wsm[i] * x[(size_t)(base+i)*DIN + t];
    out[(size_t)blockIdx.x*DIN + t] = s;
  }
}

extern "C" void kernel_launch(void* const* d_in, const int* in_sizes, int n_in,
                              void* d_out, int out_size, void* d_ws, size_t ws_size,
                              hipStream_t stream){
  (void)in_sizes; (void)n_in; (void)out_size; (void)ws_size;
  const float* x    = (const float*)d_in[0];
  const float* nq_w = (const float*)d_in[4];
  const float* nq_b = (const float*)d_in[5];
  const float* nq_ms= (const float*)d_in[6];
  const float* wq   = (const float*)d_in[7];
  const float* bq   = (const float*)d_in[8];
  const float* wk   = (const float*)d_in[9];
  const float* bk   = (const float*)d_in[10];
  const float* wv   = (const float*)d_in[11];
  const float* bv   = (const float*)d_in[12];
  const float* no_w = (const float*)d_in[13];
  const float* no_b = (const float*)d_in[14];
  const float* no_ms= (const float*)d_in[15];
  const float* o_w1 = (const float*)d_in[16];
  const float* o_b1 = (const float*)d_in[17];
  const float* o_w2 = (const float*)d_in[18];
  const float* o_b2 = (const float*)d_in[19];
  const float* pn_w = (const float*)d_in[20];
  const float* pn_b = (const float*)d_in[21];
  const float* pn_ms= (const float*)d_in[22];
  const float* p_w1 = (const float*)d_in[23];
  const float* p_b1 = (const float*)d_in[24];
  const float* p_w2 = (const float*)d_in[25];
  const float* p_b2 = (const float*)d_in[26];

  float* ws = (float*)d_ws;
  float* hcomb = (float*)((char*)d_ws + HCOMB_BYTE);

  hipMemsetAsync((char*)d_ws + (size_t)XPCNT*4, 0, 4, stream);
  k_pre<<<207, 256, 0, stream>>>(x, o_w1, o_w2, p_w1, o_b1, o_b2, p_b1, p_w2, p_b2,
                                 wq, wk, wv, nq_w, nq_b, nq_ms, ws);
  k_fused<<<NGRAPH, 512, 0, stream>>>(x, bq, bk, bv, ws, hcomb);
  k_final<<<NGRAPH, 256, 0, stream>>>(x, hcomb, ws, no_w, no_b, no_ms,
                                      pn_w, pn_b, pn_ms, (float*)d_out);
}

// Round 13
// 187.253 us; speedup vs baseline: 1.5859x; 1.2370x over previous
//
#include <hip/hip_runtime.h>
#include <stdint.h>

// FP32 in/out (R4). bf16 only for MFMA operands.
// Lessons: R6 no cooperative mega-kernel; R8/R10/R12 -- the 120-VGPR weight
// prefetch buffers spill whenever anything raises pressure (union arrays,
// launch_bounds min-waves, fused softmax temporaries). R9's exact body is
// the proven no-spill configuration. R11: 4-block/graph split regresses.
// R13 = R9 body verbatim + A1C1 preamble from k_pre finisher (pressure DOWN).

#define N_NODES 6144
#define GSIZE 24
#define NGRAPH 256
#define DIN 128
#define DH 64
#define EFF 512
#define EPSN 1e-5f

typedef __attribute__((ext_vector_type(8))) __bf16 bf16x8;
typedef __attribute__((ext_vector_type(4))) float f32x4;
union U16B { uint4 u; bf16x8 v; unsigned short s[8]; };

__device__ inline float bf2f(unsigned short u){ return __uint_as_float(((unsigned)u)<<16); }
__device__ inline unsigned short f2bf(float f){
  unsigned u = __float_as_uint(f);
  u += 0x7fff + ((u>>16)&1);
  return (unsigned short)(u>>16);
}
__device__ inline float gelu_exact(float x){ return 0.5f*x*(1.0f+erff(x*0.70710678118654752f)); }

// ---- workspace float offsets ----
#define XP     0         // 192 x 256: x col stat partials
#define A1C1   49152     // 256 floats: norm1 coeffs (k_pre finisher)
#define HP     49408     // 256 x 128: h col stat partials
#define WT1    82176
#define WT2    86272
#define PWT1   90368
#define FBo    94464     // 257 floats
#define XPCNT  95232     // 1 int (k_pre finisher counter) at byte 380928
#define WCVT_BYTE  382976    // 3 x 512 x 128 bf16
#define HCOMB_BYTE 7067648   // 6144 x 64 fp32

// ================= K1: k_pre =================
__global__ __launch_bounds__(256)
void k_pre(const float* __restrict__ x,
           const float* __restrict__ o_w1, const float* __restrict__ o_w2,
           const float* __restrict__ p_w1,
           const float* __restrict__ o_b1, const float* __restrict__ o_b2,
           const float* __restrict__ p_b1, const float* __restrict__ p_w2,
           const float* __restrict__ p_b2,
           const float* __restrict__ wq, const float* __restrict__ wk,
           const float* __restrict__ wv,
           const float* __restrict__ nq_w, const float* __restrict__ nq_b,
           const float* __restrict__ nq_ms,
           float* __restrict__ wsf){
  int t = threadIdx.x;
  int bi = blockIdx.x;
  if(bi < 192){
    int c = t & 127, h = t >> 7;
    float s = 0.f, q = 0.f;
    #pragma unroll
    for(int r = 0; r < 16; ++r){
      float v = x[(size_t)(bi*32 + h + 2*r)*DIN + c];
      s += v; q += v*v;
    }
    __shared__ float sm[256], sm2[256];
    __shared__ int lastf;
    sm[t] = s; sm2[t] = q;
    __syncthreads();
    if(t < 128){
      wsf[XP + bi*256 + t]       = sm[t] + sm[t+128];
      wsf[XP + bi*256 + 128 + t] = sm2[t] + sm2[t+128];
    }
    __syncthreads();
    if(t == 0){
      __threadfence();
      int old = atomicAdd((int*)(wsf + XPCNT), 1);
      lastf = (old == 191);
    }
    __syncthreads();
    if(!lastf) return;
    __threadfence();
    float acc = 0.f;
    for(int p = 0; p < 192; ++p) acc += wsf[XP + p*256 + t];
    sm[t] = acc;
    __syncthreads();
    if(t < 128){
      float mean = sm[t] * (1.0f / N_NODES);
      float ex2  = sm[128+t] * (1.0f / N_NODES);
      float cm   = mean * nq_ms[t];
      float var  = ex2 - 2.f*cm*mean + cm*cm;
      float rstd = rsqrtf(var + EPSN);
      float a    = nq_w[t] * rstd;
      wsf[A1C1 + t]       = a;
      wsf[A1C1 + 128 + t] = nq_b[t] - a*cm;
    }
    return;
  }
  if(bi < 195){
    const float* src; float* dst;
    if(bi == 192){ src = o_w1; dst = wsf + WT1; }
    else if(bi == 193){ src = o_w2; dst = wsf + WT2; }
    else { src = p_w1; dst = wsf + PWT1; }
    for(int p = t; p < DH*DH; p += 256){
      int r = p >> 6, c = p & 63;
      dst[c*DH + r] = src[p];
    }
    if(bi == 192){
      float* fb = wsf + FBo;
      if(t < 64){
        fb[t]       = o_b1[t];
        fb[64 + t]  = o_b2[t];
        fb[128 + t] = p_b1[t];
        fb[192 + t] = p_w2[t];
      }
      if(t == 0) fb[256] = p_b2[0];
    }
    return;
  }
  int j = bi - 195;
  int mat = j >> 2, seg = j & 3;
  const float* src = (mat==0) ? wq : (mat==1) ? wk : wv;
  unsigned short* dst = (unsigned short*)((char*)wsf + WCVT_BYTE)
                        + (size_t)mat*EFF*DIN + seg*16384;
  const float* sp = src + seg*16384;
  for(int e = t*8; e < 16384; e += 2048){
    float4 a = *(const float4*)(sp + e);
    float4 b = *(const float4*)(sp + e + 4);
    U16B o;
    o.s[0]=f2bf(a.x); o.s[1]=f2bf(a.y); o.s[2]=f2bf(a.z); o.s[3]=f2bf(a.w);
    o.s[4]=f2bf(b.x); o.s[5]=f2bf(b.y); o.s[6]=f2bf(b.z); o.s[7]=f2bf(b.w);
    *(uint4*)(dst + e) = o.u;
  }
}

// ================= K2: k_fused (R9 body verbatim; A1C1 preamble) =============
__global__ __launch_bounds__(512)
void k_fused(const float* __restrict__ x,
             const float* __restrict__ bq, const float* __restrict__ bk,
             const float* __restrict__ bv,
             float* __restrict__ ws, float* __restrict__ hcomb){
  __shared__ __align__(16) float hv[GSIZE][68];
  __shared__ float A1s[128], C1s[128];
  __shared__ __align__(16) float qs[2][GSIZE][68], ks[2][GSIZE][68], vs[2][GSIZE][68];
  __shared__ __align__(16) float S[2][GSIZE][28];

  int t = threadIdx.x, g = blockIdx.x, base = g * GSIZE;
  const unsigned short* wcvt = (const unsigned short*)((const char*)ws + WCVT_BYTE);

  if(t < 128){ A1s[t] = ws[A1C1 + t]; C1s[t] = ws[A1C1 + 128 + t]; }
  __syncthreads();

  int pipe = t >> 8, t2 = t & 255;
  int wv4 = (t >> 6) & 3, lane = t & 63, m = lane & 15, quad = lane >> 4;
  int mt = wv4 & 1, cth = wv4 >> 1;
  int node = mt*16 + m;
  int xrow = base + ((node < GSIZE) ? node : 0);

  // normalized x fragments (B operand), reused all iters
  bf16x8 xfr[4];
  #pragma unroll
  for(int kk = 0; kk < 4; kk++){
    int k0 = kk*32 + quad*8;
    float4 a = *(const float4*)(x + (size_t)xrow*DIN + k0);
    float4 bfl = *(const float4*)(x + (size_t)xrow*DIN + k0 + 4);
    U16B u;
    u.s[0] = f2bf(a.x*A1s[k0+0] + C1s[k0+0]);
    u.s[1] = f2bf(a.y*A1s[k0+1] + C1s[k0+1]);
    u.s[2] = f2bf(a.z*A1s[k0+2] + C1s[k0+2]);
    u.s[3] = f2bf(a.w*A1s[k0+3] + C1s[k0+3]);
    u.s[4] = f2bf(bfl.x*A1s[k0+4] + C1s[k0+4]);
    u.s[5] = f2bf(bfl.y*A1s[k0+5] + C1s[k0+5]);
    u.s[6] = f2bf(bfl.z*A1s[k0+6] + C1s[k0+6]);
    u.s[7] = f2bf(bfl.w*A1s[k0+7] + C1s[k0+7]);
    xfr[kk] = u.v;
  }

  // plain POD prefetch buffers (R8 spill fix)
  uint4 wbuf[6][4];
  float4 bb[6];
  {
    int hh = pipe;
    #pragma unroll
    for(int task = 0; task < 6; ++task){
      int tk = cth*6 + task;
      int mat = tk >> 2, ctm = tk & 3;
      const unsigned short* wp = wcvt + (size_t)mat*EFF*DIN
                               + (size_t)(hh*64 + ctm*16 + m)*DIN + quad*8;
      #pragma unroll
      for(int kk = 0; kk < 4; kk++) wbuf[task][kk] = *(const uint4*)(wp + kk*32);
      const float* bias = (mat==0) ? bq : (mat==1) ? bk : bv;
      bb[task] = *(const float4*)(bias + hh*64 + ctm*16 + quad*4);
    }
  }

  f32x4 a0 = {0.f,0.f,0.f,0.f}, a1 = {0.f,0.f,0.f,0.f};

  for(int iter = 0; iter < 4; ++iter){
    __syncthreads();                          // prior PV done; tiles reusable
    // ---- QKV MFMA from prefetched registers ----
    #pragma unroll
    for(int task = 0; task < 6; ++task){
      int tk = cth*6 + task;
      int mat = tk >> 2, ctm = tk & 3;
      f32x4 acc = {0.f,0.f,0.f,0.f};
      #pragma unroll
      for(int kk = 0; kk < 4; kk++){
        U16B w8; w8.u = wbuf[task][kk];
        acc = __builtin_amdgcn_mfma_f32_16x16x32_bf16(w8.v, xfr[kk], acc, 0, 0, 0);
      }
      float (*tile)[68] = (mat==0) ? qs[pipe] : (mat==1) ? ks[pipe] : vs[pipe];
      if(mt == 0 || m < 8){
        int d0 = ctm*16 + quad*4;
        tile[node][d0+0] = acc[0] + bb[task].x;
        tile[node][d0+1] = acc[1] + bb[task].y;
        tile[node][d0+2] = acc[2] + bb[task].z;
        tile[node][d0+3] = acc[3] + bb[task].w;
      }
    }
    __syncthreads();                          // tiles ready
    // prefetch next head's weights; loads fly during S + PV
    if(iter < 3){
      int hh = (iter+1)*2 + pipe;
      #pragma unroll
      for(int task = 0; task < 6; ++task){
        int tk = cth*6 + task;
        int mat = tk >> 2, ctm = tk & 3;
        const unsigned short* wp = wcvt + (size_t)mat*EFF*DIN
                                 + (size_t)(hh*64 + ctm*16 + m)*DIN + quad*8;
        #pragma unroll
        for(int kk = 0; kk < 4; kk++) wbuf[task][kk] = *(const uint4*)(wp + kk*32);
        const float* bias = (mat==0) ? bq : (mat==1) ? bk : bv;
        bb[task] = *(const float4*)(bias + hh*64 + ctm*16 + quad*4);
      }
    }
    // ---- S + softmax fused (8 lanes/row, 3 cols each, shuffle-local) ----
    if(t2 < 192){
      int row = t2 >> 3, sl = t2 & 7;
      const float4* qi = (const float4*)qs[pipe][row];
      const float4* k0p = (const float4*)ks[pipe][sl*3];
      const float4* k1p = (const float4*)ks[pipe][sl*3+1];
      const float4* k2p = (const float4*)ks[pipe][sl*3+2];
      float s0 = 0.f, s1 = 0.f, s2 = 0.f;
      #pragma unroll
      for(int d = 0; d < 16; ++d){
        float4 qv = qi[d];
        float4 ka = k0p[d], kb = k1p[d], kc = k2p[d];
        s0 += qv.x*ka.x + qv.y*ka.y + qv.z*ka.z + qv.w*ka.w;
        s1 += qv.x*kb.x + qv.y*kb.y + qv.z*kb.z + qv.w*kb.w;
        s2 += qv.x*kc.x + qv.y*kc.y + qv.z*kc.z + qv.w*kc.w;
      }
      s0 *= 0.125f; s1 *= 0.125f; s2 *= 0.125f;
      float m0 = fmaxf(fmaxf(s0, s1), s2);
      #pragma unroll
      for(int o = 1; o < 8; o <<= 1) m0 = fmaxf(m0, __shfl_xor(m0, o, 8));
      float e0 = __expf(s0-m0), e1 = __expf(s1-m0), e2 = __expf(s2-m0);
      float su = e0 + e1 + e2;
      #pragma unroll
      for(int o = 1; o < 8; o <<= 1) su += __shfl_xor(su, o, 8);
      float inv = 1.0f / (su + 1e-16f);
      S[pipe][row][sl*3]   = e0*inv;
      S[pipe][row][sl*3+1] = e1*inv;
      S[pipe][row][sl*3+2] = e2*inv;
    }
    __syncthreads();
    // ---- PV accumulate ----
    {
      int p = t2;
      if(p < 384){
        int i = p >> 4, dq = p & 15;
        #pragma unroll 8
        for(int j = 0; j < GSIZE; ++j){
          float w = S[pipe][i][j];
          float4 v = *(const float4*)&vs[pipe][j][dq*4];
          a0.x += w*v.x; a0.y += w*v.y; a0.z += w*v.z; a0.w += w*v.w;
        }
      }
      p = t2 + 256;
      if(p < 384){
        int i = p >> 4, dq = p & 15;
        #pragma unroll 8
        for(int j = 0; j < GSIZE; ++j){
          float w = S[pipe][i][j];
          float4 v = *(const float4*)&vs[pipe][j][dq*4];
          a1.x += w*v.x; a1.y += w*v.y; a1.z += w*v.z; a1.w += w*v.w;
        }
      }
    }
  }
  __syncthreads();
  if(pipe == 1){
    int p = t2;
    if(p < 384){
      int i = p >> 4, dq = p & 15;
      float4 o; o.x = a0.x*0.125f; o.y = a0.y*0.125f; o.z = a0.z*0.125f; o.w = a0.w*0.125f;
      *(float4*)&hv[i][dq*4] = o;
    }
    p = t2 + 256;
    if(p < 384){
      int i = p >> 4, dq = p & 15;
      float4 o; o.x = a1.x*0.125f; o.y = a1.y*0.125f; o.z = a1.z*0.125f; o.w = a1.w*0.125f;
      *(float4*)&hv[i][dq*4] = o;
    }
  }
  __syncthreads();
  if(pipe == 0){
    #pragma unroll
    for(int slot = 0; slot < 2; ++slot){
      int p = t2 + slot*256;
      if(p < 384){
        int i = p >> 4, dq = p & 15;
        f32x4 a = slot ? a1 : a0;
        float4 hp = *(const float4*)&hv[i][dq*4];
        const float* xr = x + (size_t)(base+i)*DIN + dq*4;
        float4 r1 = *(const float4*)xr;
        float4 r2 = *(const float4*)(xr + 64);
        float4 o;
        o.x = a.x*0.125f + hp.x + r1.x + r2.x;
        o.y = a.y*0.125f + hp.y + r1.y + r2.y;
        o.z = a.z*0.125f + hp.z + r1.z + r2.z;
        o.w = a.w*0.125f + hp.w + r1.w + r2.w;
        *(float4*)&hv[i][dq*4] = o;
        *(float4*)(hcomb + (size_t)(base+i)*DH + dq*4) = o;
      }
    }
  }
  __syncthreads();
  if(t < 64){
    float s1 = 0.f, s2 = 0.f;
    #pragma unroll
    for(int i = 0; i < GSIZE; ++i){ float v = hv[i][t]; s1 += v; s2 += v*v; }
    ws[HP + g*128 + t]      = s1;
    ws[HP + g*128 + 64 + t] = s2;
  }
}

// ================= K3: k_final =================
__global__ __launch_bounds__(256)
void k_final(const float* __restrict__ x,
             const float* __restrict__ hbuf, const float* __restrict__ ws,
             const float* __restrict__ no_w, const float* __restrict__ no_b,
             const float* __restrict__ no_ms,
             const float* __restrict__ pn_w, const float* __restrict__ pn_b,
             const float* __restrict__ pn_ms,
             float* __restrict__ out){
  const float* pwt1 = ws + PWT1;
  const float* fb   = ws + FBo;

  __shared__ float wt1s[64][64], wt2s[64][64];
  __shared__ float hs[GSIZE][DH];
  __shared__ float hn[GSIZE][DH];
  __shared__ float ts[GSIZE][DH];
  __shared__ float A2[DH], C2[DH];
  __shared__ float a3[DH], c3[DH];
  __shared__ float scores[GSIZE], wsm[GSIZE];
  __shared__ float redA[256], redB[256];

  int t = threadIdx.x;
  int base = blockIdx.x * GSIZE;

  for(int p = t; p < DH*DH; p += 256){
    wt1s[p>>6][p&63] = ws[WT1 + p];
    wt2s[p>>6][p&63] = ws[WT2 + p];
  }
  {
    int c = t & 63, grp = t >> 6;
    float s1 = 0.f, s2 = 0.f;
    for(int p = grp; p < NGRAPH; p += 4){
      s1 += ws[HP + p*128 + c];
      s2 += ws[HP + p*128 + 64 + c];
    }
    redA[t] = s1; redB[t] = s2;
  }
  __syncthreads();
  if(t < DH){
    float s1 = redA[t] + redA[t+64] + redA[t+128] + redA[t+192];
    float s2 = redB[t] + redB[t+64] + redB[t+128] + redB[t+192];
    float mean = s1 * (1.0f / N_NODES);
    float ex2  = s2 * (1.0f / N_NODES);
    float cm   = mean * no_ms[t];
    float var  = ex2 - 2.f*cm*mean + cm*cm;
    float rstd = rsqrtf(var + EPSN);
    float a    = no_w[t] * rstd;
    A2[t] = a; C2[t] = no_b[t] - a*cm;
  }
  __syncthreads();
  for(int p = t; p < GSIZE*DH; p += 256){
    int i = p >> 6, d = p & 63;
    float hvv = hbuf[(size_t)(base+i)*DH + d];
    hs[i][d] = hvv;
    hn[i][d] = A2[d]*hvv + C2[d];
  }
  __syncthreads();
  for(int p = t; p < GSIZE*DH; p += 256){
    int i = p >> 6, c = p & 63;
    float s = fb[c];
    #pragma unroll
    for(int k = 0; k < DH; k++) s += hn[i][k] * wt1s[k][c];
    ts[i][c] = gelu_exact(s);
  }
  __syncthreads();
  for(int p = t; p < GSIZE*DH; p += 256){
    int i = p >> 6, c = p & 63;
    float s = fb[64 + c];
    #pragma unroll
    for(int k = 0; k < DH; k++) s += ts[i][k] * wt2s[k][c];
    hs[i][c] = hs[i][c] + s;
  }
  __syncthreads();
  if(t < DH){
    float s1 = 0.f, s2 = 0.f;
    for(int i = 0; i < GSIZE; i++){ float v = hs[i][t]; s1 += v; s2 += v*v; }
    float mean = s1 * (1.0f / GSIZE);
    float ex2  = s2 * (1.0f / GSIZE);
    float cm   = mean * pn_ms[t];
    float var  = ex2 - 2.f*cm*mean + cm*cm;
    float rstd = rsqrtf(var + EPSN);
    float a    = pn_w[t] * rstd;
    a3[t] = a; c3[t] = pn_b[t] - a*cm;
  }
  __syncthreads();
  for(int p = t; p < GSIZE*DH; p += 256){
    int i = p >> 6, d = p & 63;
    hn[i][d] = a3[d]*hs[i][d] + c3[d];
  }
  __syncthreads();
  for(int p = t; p < GSIZE*DH; p += 256){
    int i = p >> 6, c = p & 63;
    float s = fb[128 + c];
    #pragma unroll
    for(int k = 0; k < DH; k++) s += hn[i][k] * pwt1[k*DH + c];
    ts[i][c] = gelu_exact(s);
  }
  __syncthreads();
  if(t < GSIZE){
    float s = fb[256];
    for(int c = 0; c < DH; c++) s += ts[t][c] * fb[192 + c];
    scores[t] = s;
  }
  __syncthreads();
  if(t < GSIZE){
    float mx = -1e30f;
    for(int j = 0; j < GSIZE; j++) mx = fmaxf(mx, scores[j]);
    float sum = 0.f;
    for(int j = 0; j < GSIZE; j++) sum += __expf(scores[j] - mx);
    wsm[t] = __expf(scores[t] - mx) / (sum + 1e-16f);
  }
  __syncthreads();
  if(t < DIN){
    float s = 0.f;
    #pragma unroll 8
    for(int i = 0; i < GSIZE; i++) s += wsm[i] * x[(size_t)(base+i)*DIN + t];
    out[(size_t)blockIdx.x*DIN + t] = s;
  }
}

extern "C" void kernel_launch(void* const* d_in, const int* in_sizes, int n_in,
                              void* d_out, int out_size, void* d_ws, size_t ws_size,
                              hipStream_t stream){
  (void)in_sizes; (void)n_in; (void)out_size; (void)ws_size;
  const float* x    = (const float*)d_in[0];
  const float* nq_w = (const float*)d_in[4];
  const float* nq_b = (const float*)d_in[5];
  const float* nq_ms= (const float*)d_in[6];
  const float* wq   = (const float*)d_in[7];
  const float* bq   = (const float*)d_in[8];
  const float* wk   = (const float*)d_in[9];
  const float* bk   = (const float*)d_in[10];
  const float* wv   = (const float*)d_in[11];
  const float* bv   = (const float*)d_in[12];
  const float* no_w = (const float*)d_in[13];
  const float* no_b = (const float*)d_in[14];
  const float* no_ms= (const float*)d_in[15];
  const float* o_w1 = (const float*)d_in[16];
  const float* o_b1 = (const float*)d_in[17];
  const float* o_w2 = (const float*)d_in[18];
  const float* o_b2 = (const float*)d_in[19];
  const float* pn_w = (const float*)d_in[20];
  const float* pn_b = (const float*)d_in[21];
  const float* pn_ms= (const float*)d_in[22];
  const float* p_w1 = (const float*)d_in[23];
  const float* p_b1 = (const float*)d_in[24];
  const float* p_w2 = (const float*)d_in[25];
  const float* p_b2 = (const float*)d_in[26];

  float* ws = (float*)d_ws;
  float* hcomb = (float*)((char*)d_ws + HCOMB_BYTE);

  hipMemsetAsync((char*)d_ws + (size_t)XPCNT*4, 0, 4, stream);
  k_pre<<<207, 256, 0, stream>>>(x, o_w1, o_w2, p_w1, o_b1, o_b2, p_b1, p_w2, p_b2,
                                 wq, wk, wv, nq_w, nq_b, nq_ms, ws);
  k_fused<<<NGRAPH, 512, 0, stream>>>(x, bq, bk, bv, ws, hcomb);
  k_final<<<NGRAPH, 256, 0, stream>>>(x, hcomb, ws, no_w, no_b, no_ms,
                                      pn_w, pn_b, pn_ms, (float*)d_out);
}

// Round 14
// 181.448 us; speedup vs baseline: 1.6366x; 1.0320x over previous
//
#include <hip/hip_runtime.h>
#include <stdint.h>

// FP32 in/out (R4). bf16 only for MFMA operands.
// FINAL CONFIG = round-8 submission, measured 182.2 us (best of 13 rounds).
// Ledger: R6 mega-kernel +150us; R8 union-array prefetch spills +75us;
// R10 launch_bounds min-waves caps VGPR -> spill +115us; R11 4-block split
// +90us; R12 fused softmax -> spill +45us; R13 finisher/memset +5us.
// k_fused: 256 blocks x 512 thr, 2 head-pipes x 4 iters, POD register
// weight prefetch one head ahead (VGPR 120 -- allocator knife-edge at 128).

#define N_NODES 6144
#define GSIZE 24
#define NGRAPH 256
#define DIN 128
#define DH 64
#define EFF 512
#define EPSN 1e-5f

typedef __attribute__((ext_vector_type(8))) __bf16 bf16x8;
typedef __attribute__((ext_vector_type(4))) float f32x4;
union U16B { uint4 u; bf16x8 v; unsigned short s[8]; };

__device__ inline float bf2f(unsigned short u){ return __uint_as_float(((unsigned)u)<<16); }
__device__ inline unsigned short f2bf(float f){
  unsigned u = __float_as_uint(f);
  u += 0x7fff + ((u>>16)&1);
  return (unsigned short)(u>>16);
}
__device__ inline float gelu_exact(float x){ return 0.5f*x*(1.0f+erff(x*0.70710678118654752f)); }

// ---- workspace float offsets ----
#define XP    0         // 192 x 256 floats: x col sum/sumsq partials
#define HP    49152     // 256 x 128 floats: h col stat partials
#define WT1   81920
#define WT2   86016
#define PWT1  90112
#define FBo   94208     // 257 floats
#define WCVT_BYTE  385024   // 3 x 512 x 128 bf16 = 393216 B
#define HCOMB_BYTE 778240   // 6144 x 64 fp32

// ================= K1: k_pre =================
// blocks 0..191: x col-stat partials (32 rows each)
// blocks 192..194: transpose o_w1/o_w2/p_w1 (+bias staging in 192)
// blocks 195..206: wq/wk/wv -> bf16 (12 segments)
__global__ __launch_bounds__(256)
void k_pre(const float* __restrict__ x,
           const float* __restrict__ o_w1, const float* __restrict__ o_w2,
           const float* __restrict__ p_w1,
           const float* __restrict__ o_b1, const float* __restrict__ o_b2,
           const float* __restrict__ p_b1, const float* __restrict__ p_w2,
           const float* __restrict__ p_b2,
           const float* __restrict__ wq, const float* __restrict__ wk,
           const float* __restrict__ wv,
           float* __restrict__ wsf){
  int t = threadIdx.x;
  int bi = blockIdx.x;
  if(bi < 192){
    int c = t & 127, h = t >> 7;
    float s = 0.f, q = 0.f;
    #pragma unroll
    for(int r = 0; r < 16; ++r){
      float v = x[(size_t)(bi*32 + h + 2*r)*DIN + c];
      s += v; q += v*v;
    }
    __shared__ float sm[256], sm2[256];
    sm[t] = s; sm2[t] = q;
    __syncthreads();
    if(t < 128){
      wsf[XP + bi*256 + t]       = sm[t] + sm[t+128];
      wsf[XP + bi*256 + 128 + t] = sm2[t] + sm2[t+128];
    }
    return;
  }
  if(bi < 195){
    const float* src; float* dst;
    if(bi == 192){ src = o_w1; dst = wsf + WT1; }
    else if(bi == 193){ src = o_w2; dst = wsf + WT2; }
    else { src = p_w1; dst = wsf + PWT1; }
    for(int p = t; p < DH*DH; p += 256){
      int r = p >> 6, c = p & 63;
      dst[c*DH + r] = src[p];
    }
    if(bi == 192){
      float* fb = wsf + FBo;
      if(t < 64){
        fb[t]       = o_b1[t];
        fb[64 + t]  = o_b2[t];
        fb[128 + t] = p_b1[t];
        fb[192 + t] = p_w2[t];
      }
      if(t == 0) fb[256] = p_b2[0];
    }
    return;
  }
  int j = bi - 195;               // 0..11
  int mat = j >> 2, seg = j & 3;
  const float* src = (mat==0) ? wq : (mat==1) ? wk : wv;
  unsigned short* dst = (unsigned short*)((char*)wsf + WCVT_BYTE)
                        + (size_t)mat*EFF*DIN + seg*16384;
  const float* sp = src + seg*16384;
  for(int e = t*8; e < 16384; e += 2048){
    float4 a = *(const float4*)(sp + e);
    float4 b = *(const float4*)(sp + e + 4);
    U16B o;
    o.s[0]=f2bf(a.x); o.s[1]=f2bf(a.y); o.s[2]=f2bf(a.z); o.s[3]=f2bf(a.w);
    o.s[4]=f2bf(b.x); o.s[5]=f2bf(b.y); o.s[6]=f2bf(b.z); o.s[7]=f2bf(b.w);
    *(uint4*)(dst + e) = o.u;
  }
}

// ================= K2: k_fused =================
__global__ __launch_bounds__(512)
void k_fused(const float* __restrict__ x,
             const float* __restrict__ bq, const float* __restrict__ bk,
             const float* __restrict__ bv,
             const float* __restrict__ nq_w, const float* __restrict__ nq_b,
             const float* __restrict__ nq_ms,
             float* __restrict__ ws, float* __restrict__ hcomb){
  __shared__ __align__(16) char arena[52224];
  float (*hv)[68] = (float(*)[68])(arena);                    // 0..6528
  float* A1 = (float*)(arena + 6528);
  float* C1 = (float*)(arena + 7040);
  float (*qs)[GSIZE][68] = (float(*)[GSIZE][68])(arena + 7552);
  float (*ks)[GSIZE][68] = (float(*)[GSIZE][68])(arena + 20608);
  float (*vs)[GSIZE][68] = (float(*)[GSIZE][68])(arena + 33664);
  float (*S)[GSIZE][28]  = (float(*)[GSIZE][28])(arena + 46720);
  float* redA = (float*)(arena + 7552);   // alias qs (preamble only)
  float* redB = (float*)(arena + 11648);

  int t = threadIdx.x, g = blockIdx.x, base = g * GSIZE;
  const unsigned short* wcvt = (const unsigned short*)((const char*)ws + WCVT_BYTE);

  // ---- reduce x col-stat partials -> A1/C1 ----
  {
    int c = t & 127, grp = t >> 7;   // grp 0..3
    float s = 0.f, q = 0.f;
    for(int p = grp*48; p < grp*48 + 48; ++p){
      s += ws[XP + p*256 + c];
      q += ws[XP + p*256 + 128 + c];
    }
    redA[t] = s; redB[t] = q;
  }
  __syncthreads();
  if(t < 128){
    float s = redA[t] + redA[t+128] + redA[t+256] + redA[t+384];
    float q = redB[t] + redB[t+128] + redB[t+256] + redB[t+384];
    float mean = s * (1.0f / N_NODES);
    float ex2  = q * (1.0f / N_NODES);
    float cm   = mean * nq_ms[t];
    float var  = ex2 - 2.f*cm*mean + cm*cm;
    float rstd = rsqrtf(var + EPSN);
    float a    = nq_w[t] * rstd;
    A1[t] = a; C1[t] = nq_b[t] - a*cm;
  }
  __syncthreads();

  int pipe = t >> 8, t2 = t & 255;
  int wv4 = (t >> 6) & 3, lane = t & 63, m = lane & 15, quad = lane >> 4;
  int mt = wv4 & 1, cth = wv4 >> 1;
  int node = mt*16 + m;
  int xrow = base + node; if(xrow > N_NODES-1) xrow = N_NODES-1;

  // normalized x fragments (B operand), per wave's m-tile, reused all iters
  bf16x8 xfr[4];
  #pragma unroll
  for(int kk = 0; kk < 4; kk++){
    int k0 = kk*32 + quad*8;
    float4 a = *(const float4*)(x + (size_t)xrow*DIN + k0);
    float4 b = *(const float4*)(x + (size_t)xrow*DIN + k0 + 4);
    U16B u;
    u.s[0] = f2bf(a.x*A1[k0+0] + C1[k0+0]);
    u.s[1] = f2bf(a.y*A1[k0+1] + C1[k0+1]);
    u.s[2] = f2bf(a.z*A1[k0+2] + C1[k0+2]);
    u.s[3] = f2bf(a.w*A1[k0+3] + C1[k0+3]);
    u.s[4] = f2bf(b.x*A1[k0+4] + C1[k0+4]);
    u.s[5] = f2bf(b.y*A1[k0+5] + C1[k0+5]);
    u.s[6] = f2bf(b.z*A1[k0+6] + C1[k0+6]);
    u.s[7] = f2bf(b.w*A1[k0+7] + C1[k0+7]);
    xfr[kk] = u.v;
  }

  // plain POD prefetch buffers (R8 spill fix: no union arrays, no lambda)
  uint4 wbuf[6][4];
  float4 bb[6];
  // prologue prefetch for iter 0 (head = pipe)
  {
    int hh = pipe;
    #pragma unroll
    for(int task = 0; task < 6; ++task){
      int tk = cth*6 + task;
      int mat = tk >> 2, ctm = tk & 3;
      const unsigned short* wp = wcvt + (size_t)mat*EFF*DIN
                               + (size_t)(hh*64 + ctm*16 + m)*DIN + quad*8;
      #pragma unroll
      for(int kk = 0; kk < 4; kk++) wbuf[task][kk] = *(const uint4*)(wp + kk*32);
      const float* bias = (mat==0) ? bq : (mat==1) ? bk : bv;
      bb[task] = *(const float4*)(bias + hh*64 + ctm*16 + quad*4);
    }
  }

  f32x4 a0 = {0.f,0.f,0.f,0.f}, a1 = {0.f,0.f,0.f,0.f};

  for(int iter = 0; iter < 4; ++iter){
    __syncthreads();                          // prior PV done; tiles reusable
    // ---- QKV MFMA from prefetched registers ----
    #pragma unroll
    for(int task = 0; task < 6; ++task){
      int tk = cth*6 + task;
      int mat = tk >> 2, ctm = tk & 3;
      f32x4 acc = {0.f,0.f,0.f,0.f};
      #pragma unroll
      for(int kk = 0; kk < 4; kk++){
        U16B w8; w8.u = wbuf[task][kk];
        acc = __builtin_amdgcn_mfma_f32_16x16x32_bf16(w8.v, xfr[kk], acc, 0, 0, 0);
      }
      float (*tile)[68] = (mat==0) ? qs[pipe] : (mat==1) ? ks[pipe] : vs[pipe];
      if(mt == 0 || m < 8){
        int d0 = ctm*16 + quad*4;
        tile[node][d0+0] = acc[0] + bb[task].x;
        tile[node][d0+1] = acc[1] + bb[task].y;
        tile[node][d0+2] = acc[2] + bb[task].z;
        tile[node][d0+3] = acc[3] + bb[task].w;
      }
    }
    __syncthreads();                          // tiles ready
    // prefetch next head's weights; loads fly during S + PV
    if(iter < 3){
      int hh = (iter+1)*2 + pipe;
      #pragma unroll
      for(int task = 0; task < 6; ++task){
        int tk = cth*6 + task;
        int mat = tk >> 2, ctm = tk & 3;
        const unsigned short* wp = wcvt + (size_t)mat*EFF*DIN
                                 + (size_t)(hh*64 + ctm*16 + m)*DIN + quad*8;
        #pragma unroll
        for(int kk = 0; kk < 4; kk++) wbuf[task][kk] = *(const uint4*)(wp + kk*32);
        const float* bias = (mat==0) ? bq : (mat==1) ? bk : bv;
        bb[task] = *(const float4*)(bias + hh*64 + ctm*16 + quad*4);
      }
    }
    // ---- S + softmax fused (8 lanes/row, 3 cols each, shuffle-local) ----
    if(t2 < 192){
      int row = t2 >> 3, sl = t2 & 7;
      const float4* qi = (const float4*)qs[pipe][row];
      const float4* k0p = (const float4*)ks[pipe][sl*3];
      const float4* k1p = (const float4*)ks[pipe][sl*3+1];
      const float4* k2p = (const float4*)ks[pipe][sl*3+2];
      float s0 = 0.f, s1 = 0.f, s2 = 0.f;
      #pragma unroll
      for(int d = 0; d < 16; ++d){
        float4 qv = qi[d];
        float4 ka = k0p[d], kb = k1p[d], kc = k2p[d];
        s0 += qv.x*ka.x + qv.y*ka.y + qv.z*ka.z + qv.w*ka.w;
        s1 += qv.x*kb.x + qv.y*kb.y + qv.z*kb.z + qv.w*kb.w;
        s2 += qv.x*kc.x + qv.y*kc.y + qv.z*kc.z + qv.w*kc.w;
      }
      s0 *= 0.125f; s1 *= 0.125f; s2 *= 0.125f;
      float m0 = fmaxf(fmaxf(s0, s1), s2);
      #pragma unroll
      for(int o = 1; o < 8; o <<= 1) m0 = fmaxf(m0, __shfl_xor(m0, o, 8));
      float e0 = __expf(s0-m0), e1 = __expf(s1-m0), e2 = __expf(s2-m0);
      float su = e0 + e1 + e2;
      #pragma unroll
      for(int o = 1; o < 8; o <<= 1) su += __shfl_xor(su, o, 8);
      float inv = 1.0f / (su + 1e-16f);
      S[pipe][row][sl*3]   = e0*inv;
      S[pipe][row][sl*3+1] = e1*inv;
      S[pipe][row][sl*3+2] = e2*inv;
    }
    __syncthreads();
    // ---- PV accumulate ----
    {
      int p = t2;
      if(p < 384){
        int i = p >> 4, dq = p & 15;
        #pragma unroll 8
        for(int j = 0; j < GSIZE; ++j){
          float w = S[pipe][i][j];
          float4 v = *(const float4*)&vs[pipe][j][dq*4];
          a0.x += w*v.x; a0.y += w*v.y; a0.z += w*v.z; a0.w += w*v.w;
        }
      }
      p = t2 + 256;
      if(p < 384){
        int i = p >> 4, dq = p & 15;
        #pragma unroll 8
        for(int j = 0; j < GSIZE; ++j){
          float w = S[pipe][i][j];
          float4 v = *(const float4*)&vs[pipe][j][dq*4];
          a1.x += w*v.x; a1.y += w*v.y; a1.z += w*v.z; a1.w += w*v.w;
        }
      }
    }
  }
  __syncthreads();
  if(pipe == 1){
    int p = t2;
    if(p < 384){
      int i = p >> 4, dq = p & 15;
      float4 o; o.x = a0.x*0.125f; o.y = a0.y*0.125f; o.z = a0.z*0.125f; o.w = a0.w*0.125f;
      *(float4*)&hv[i][dq*4] = o;
    }
    p = t2 + 256;
    if(p < 384){
      int i = p >> 4, dq = p & 15;
      float4 o; o.x = a1.x*0.125f; o.y = a1.y*0.125f; o.z = a1.z*0.125f; o.w = a1.w*0.125f;
      *(float4*)&hv[i][dq*4] = o;
    }
  }
  __syncthreads();
  if(pipe == 0){
    #pragma unroll
    for(int slot = 0; slot < 2; ++slot){
      int p = t2 + slot*256;
      if(p < 384){
        int i = p >> 4, dq = p & 15;
        f32x4 a = slot ? a1 : a0;
        float4 hp = *(const float4*)&hv[i][dq*4];
        const float* xr = x + (size_t)(base+i)*DIN + dq*4;
        float4 r1 = *(const float4*)xr;
        float4 r2 = *(const float4*)(xr + 64);
        float4 o;
        o.x = a.x*0.125f + hp.x + r1.x + r2.x;
        o.y = a.y*0.125f + hp.y + r1.y + r2.y;
        o.z = a.z*0.125f + hp.z + r1.z + r2.z;
        o.w = a.w*0.125f + hp.w + r1.w + r2.w;
        *(float4*)&hv[i][dq*4] = o;
        *(float4*)(hcomb + (size_t)(base+i)*DH + dq*4) = o;
      }
    }
  }
  __syncthreads();
  if(t < 64){
    float s1 = 0.f, s2 = 0.f;
    #pragma unroll
    for(int i = 0; i < GSIZE; ++i){ float v = hv[i][t]; s1 += v; s2 += v*v; }
    ws[HP + g*128 + t]      = s1;
    ws[HP + g*128 + 64 + t] = s2;
  }
}

// ================= K3: k_final =================
__global__ __launch_bounds__(256)
void k_final(const float* __restrict__ x,
             const float* __restrict__ hbuf, const float* __restrict__ ws,
             const float* __restrict__ no_w, const float* __restrict__ no_b,
             const float* __restrict__ no_ms,
             const float* __restrict__ pn_w, const float* __restrict__ pn_b,
             const float* __restrict__ pn_ms,
             float* __restrict__ out){
  const float* wt1  = ws + WT1;
  const float* wt2  = ws + WT2;
  const float* pwt1 = ws + PWT1;
  const float* fb   = ws + FBo;

  __shared__ float hs[GSIZE][DH+1];
  __shared__ float hn[GSIZE][DH+1];
  __shared__ float ts[GSIZE][DH+1];
  __shared__ float A2[DH], C2[DH];
  __shared__ float a3[DH], c3[DH];
  __shared__ float scores[GSIZE], wsm[GSIZE];
  __shared__ float redA[256], redB[256];

  int t = threadIdx.x;
  int base = blockIdx.x * GSIZE;

  {
    int c = t & 63, grp = t >> 6;
    float s1 = 0.f, s2 = 0.f;
    for(int p = grp; p < NGRAPH; p += 4){
      s1 += ws[HP + p*128 + c];
      s2 += ws[HP + p*128 + 64 + c];
    }
    redA[t] = s1; redB[t] = s2;
  }
  __syncthreads();
  if(t < DH){
    float s1 = redA[t] + redA[t+64] + redA[t+128] + redA[t+192];
    float s2 = redB[t] + redB[t+64] + redB[t+128] + redB[t+192];
    float mean = s1 * (1.0f / N_NODES);
    float ex2  = s2 * (1.0f / N_NODES);
    float cm   = mean * no_ms[t];
    float var  = ex2 - 2.f*cm*mean + cm*cm;
    float rstd = rsqrtf(var + EPSN);
    float a    = no_w[t] * rstd;
    A2[t] = a; C2[t] = no_b[t] - a*cm;
  }
  __syncthreads();
  for(int p = t; p < GSIZE*DH; p += 256){
    int i = p >> 6, d = p & 63;
    float hvv = hbuf[(size_t)(base+i)*DH + d];
    hs[i][d] = hvv;
    hn[i][d] = A2[d]*hvv + C2[d];
  }
  __syncthreads();
  for(int p = t; p < GSIZE*DH; p += 256){
    int i = p >> 6, c = p & 63;
    float s = fb[c];
    #pragma unroll
    for(int k = 0; k < DH; k++) s += hn[i][k] * wt1[k*DH + c];
    ts[i][c] = gelu_exact(s);
  }
  __syncthreads();
  for(int p = t; p < GSIZE*DH; p += 256){
    int i = p >> 6, c = p & 63;
    float s = fb[64 + c];
    #pragma unroll
    for(int k = 0; k < DH; k++) s += ts[i][k] * wt2[k*DH + c];
    hs[i][c] = hs[i][c] + s;
  }
  __syncthreads();
  if(t < DH){
    float s1 = 0.f, s2 = 0.f;
    for(int i = 0; i < GSIZE; i++){ float v = hs[i][t]; s1 += v; s2 += v*v; }
    float mean = s1 * (1.0f / GSIZE);
    float ex2  = s2 * (1.0f / GSIZE);
    float cm   = mean * pn_ms[t];
    float var  = ex2 - 2.f*cm*mean + cm*cm;
    float rstd = rsqrtf(var + EPSN);
    float a    = pn_w[t] * rstd;
    a3[t] = a; c3[t] = pn_b[t] - a*cm;
  }
  __syncthreads();
  for(int p = t; p < GSIZE*DH; p += 256){
    int i = p >> 6, d = p & 63;
    hn[i][d] = a3[d]*hs[i][d] + c3[d];
  }
  __syncthreads();
  for(int p = t; p < GSIZE*DH; p += 256){
    int i = p >> 6, c = p & 63;
    float s = fb[128 + c];
    #pragma unroll
    for(int k = 0; k < DH; k++) s += hn[i][k] * pwt1[k*DH + c];
    ts[i][c] = gelu_exact(s);
  }
  __syncthreads();
  if(t < GSIZE){
    float s = fb[256];
    for(int c = 0; c < DH; c++) s += ts[t][c] * fb[192 + c];
    scores[t] = s;
  }
  __syncthreads();
  if(t < GSIZE){
    float mx = -1e30f;
    for(int j = 0; j < GSIZE; j++) mx = fmaxf(mx, scores[j]);
    float sum = 0.f;
    for(int j = 0; j < GSIZE; j++) sum += __expf(scores[j] - mx);
    wsm[t] = __expf(scores[t] - mx) / (sum + 1e-16f);
  }
  __syncthreads();
  if(t < DIN){
    float s = 0.f;
    #pragma unroll 8
    for(int i = 0; i < GSIZE; i++) s += wsm[i] * x[(size_t)(base+i)*DIN + t];
    out[(size_t)blockIdx.x*DIN + t] = s;
  }
}

extern "C" void kernel_launch(void* const* d_in, const int* in_sizes, int n_in,
                              void* d_out, int out_size, void* d_ws, size_t ws_size,
                              hipStream_t stream){
  (void)in_sizes; (void)n_in; (void)out_size; (void)ws_size;
  const float* x    = (const float*)d_in[0];
  const float* nq_w = (const float*)d_in[4];
  const float* nq_b = (const float*)d_in[5];
  const float* nq_ms= (const float*)d_in[6];
  const float* wq   = (const float*)d_in[7];
  const float* bq   = (const float*)d_in[8];
  const float* wk   = (const float*)d_in[9];
  const float* bk   = (const float*)d_in[10];
  const float* wv   = (const float*)d_in[11];
  const float* bv   = (const float*)d_in[12];
  const float* no_w = (const float*)d_in[13];
  const float* no_b = (const float*)d_in[14];
  const float* no_ms= (const float*)d_in[15];
  const float* o_w1 = (const float*)d_in[16];
  const float* o_b1 = (const float*)d_in[17];
  const float* o_w2 = (const float*)d_in[18];
  const float* o_b2 = (const float*)d_in[19];
  const float* pn_w = (const float*)d_in[20];
  const float* pn_b = (const float*)d_in[21];
  const float* pn_ms= (const float*)d_in[22];
  const float* p_w1 = (const float*)d_in[23];
  const float* p_b1 = (const float*)d_in[24];
  const float* p_w2 = (const float*)d_in[25];
  const float* p_b2 = (const float*)d_in[26];

  float* ws = (float*)d_ws;
  float* hcomb = (float*)((char*)d_ws + HCOMB_BYTE);

  k_pre<<<207, 256, 0, stream>>>(x, o_w1, o_w2, p_w1, o_b1, o_b2, p_b1, p_w2, p_b2,
                                 wq, wk, wv, ws);
  k_fused<<<NGRAPH, 512, 0, stream>>>(x, bq, bk, bv, nq_w, nq_b, nq_ms, ws, hcomb);
  k_final<<<NGRAPH, 256, 0, stream>>>(x, hcomb, ws, no_w, no_b, no_ms,
                                      pn_w, pn_b, pn_ms, (float*)d_out);
}